// Round 5
// baseline (1267.593 us; speedup 1.0000x reference)
//
#include <hip/hip_runtime.h>

// DIAGNOSTIC ROUND: all-f32 pipeline (no bf16, no MFMA) to bisect structure
// vs precision. Same 5-dispatch structure, scan/carry logic, and d_out
// aliasing as r4:
//   d_out = [0,64MB) output f32 | [64,128MB) inner-real f32.
//   BuRe lives in inner-real region (K1 writes, K2a reads, K3 scan reads then
//   overwrites per-thread with Re(pre-state)).
//   BuIm lives in output region (K1 writes, K2a reads, K3 scan reads own rows
//   before the barrier; epilogue overwrites same rows, same thread = col).

// ---------------------------------------------------------------------------
// K0f: weights in f32.
// W1fre/W1fim: [h][n] = gam[n]*B_re/im[n][h]            (256x256 each)
// W2f:         [k][o], k<512: even->C_re[o][k/2], odd->-C_im[o][k/2];
//                      k>=512 -> D[o][k-512]            (768x256)
// ---------------------------------------------------------------------------
__global__ void k0f(const float* __restrict__ nu_log, const float* __restrict__ theta_log,
                    const float* __restrict__ gamma_log,
                    const float* __restrict__ B_re, const float* __restrict__ B_im,
                    const float* __restrict__ C_re, const float* __restrict__ C_im,
                    const float* __restrict__ Dm,
                    float* __restrict__ W1fre, float* __restrict__ W1fim,
                    float* __restrict__ W2f,
                    float* __restrict__ lamre, float* __restrict__ lamim,
                    float* __restrict__ lamLre, float* __restrict__ lamLim) {
  int idx = blockIdx.x * 256 + threadIdx.x;
  if (idx < 65536) {
    int n = idx & 255, h = idx >> 8;
    W1fre[idx] = expf(gamma_log[n]) * B_re[n * 256 + h];
  } else if (idx < 131072) {
    int j = idx - 65536;
    int n = j & 255, h = j >> 8;
    W1fim[j] = expf(gamma_log[n]) * B_im[n * 256 + h];
  } else if (idx < 327680) {
    int j = idx - 131072;
    int k = j >> 8, o = j & 255;
    float v;
    if (k < 512) { int n = k >> 1; v = (k & 1) ? -C_im[o * 256 + n] : C_re[o * 256 + n]; }
    else         { v = Dm[o * 256 + (k - 512)]; }
    W2f[j] = v;
  } else if (idx < 327936) {
    int n = idx - 327680;
    float la = expf(-expf(nu_log[n]));
    float th = expf(theta_log[n]);
    float lr = la * cosf(th), li = la * sinf(th);
    lamre[n] = lr; lamim[n] = li;
    float r = lr, i = li;
    #pragma unroll
    for (int t = 0; t < 5; ++t) { float nr = r * r - i * i; float ni = 2.f * r * i; r = nr; i = ni; }
    lamLre[n] = r; lamLim[n] = i;
  }
}

// ---------------------------------------------------------------------------
// K1f: Bu = input @ W1^T, pure f32 VALU. Block = 32 rows; thread n holds 32
// complex accumulators (static register indices via full unroll).
// ---------------------------------------------------------------------------
__global__ __launch_bounds__(256, 2) void k1f(const float* __restrict__ in,
                                              const float* __restrict__ W1fre,
                                              const float* __restrict__ W1fim,
                                              float* __restrict__ BuRe,
                                              float* __restrict__ BuIm) {
  __shared__ float lu[32 * 256];
  int tid = threadIdx.x;
  size_t row0 = (size_t)blockIdx.x * 32;

  #pragma unroll
  for (int pass = 0; pass < 8; ++pass) {
    int m = pass * 4 + (tid >> 6);
    int h0 = (tid & 63) * 4;
    *reinterpret_cast<float4*>(&lu[m * 256 + h0]) =
        *reinterpret_cast<const float4*>(in + (row0 + m) * 256 + h0);
  }
  __syncthreads();

  int n = tid;
  float ar[32], ai[32];
  #pragma unroll
  for (int m = 0; m < 32; ++m) { ar[m] = 0.f; ai[m] = 0.f; }

  for (int h = 0; h < 256; h += 4) {
    float wre[4], wim[4];
    #pragma unroll
    for (int i = 0; i < 4; ++i) {
      wre[i] = W1fre[(h + i) * 256 + n];
      wim[i] = W1fim[(h + i) * 256 + n];
    }
    #pragma unroll
    for (int m = 0; m < 32; ++m) {
      float4 u4 = *reinterpret_cast<const float4*>(&lu[m * 256 + h]);
      ar[m] += u4.x * wre[0] + u4.y * wre[1] + u4.z * wre[2] + u4.w * wre[3];
      ai[m] += u4.x * wim[0] + u4.y * wim[1] + u4.z * wim[2] + u4.w * wim[3];
    }
  }

  #pragma unroll
  for (int m = 0; m < 32; ++m) {
    BuRe[(row0 + m) * 256 + n] = ar[m];
    BuIm[(row0 + m) * 256 + n] = ai[m];
  }
}

// ---------------------------------------------------------------------------
// K2a: per-chunk local reduction x_c = sum_j lam^(31-j) Bu_j  (unchanged).
// ---------------------------------------------------------------------------
__global__ void k2a_local(const float* __restrict__ BuRe, const float* __restrict__ BuIm,
                          const float* __restrict__ lamre, const float* __restrict__ lamim,
                          float2* __restrict__ cl) {
  int b = blockIdx.x >> 7, c = blockIdx.x & 127, n = threadIdx.x;
  size_t row0 = (size_t)b * 4096 + c * 32;
  float lr = lamre[n], li = lamim[n];
  float xr = 0.f, xi = 0.f;
  #pragma unroll 8
  for (int j = 0; j < 32; ++j) {
    size_t idx = (row0 + j) * 256 + n;
    float br = BuRe[idx], bi = BuIm[idx];
    float nr = lr * xr - li * xi + br;
    float ni = lr * xi + li * xr + bi;
    xr = nr; xi = ni;
  }
  cl[((size_t)b * 128 + c) * 256 + n] = make_float2(xr, xi);
}

// ---------------------------------------------------------------------------
// K2b: scan over 128 chunk carries per (b,n)  (unchanged).
// ---------------------------------------------------------------------------
__global__ void k2b_scan(const float2* __restrict__ cl, float2* __restrict__ cin,
                         const float* __restrict__ lamLre, const float* __restrict__ lamLim) {
  int b = blockIdx.x, n = threadIdx.x;
  float lr = lamLre[n], li = lamLim[n];
  float sr = 0.f, si = 0.f;
  #pragma unroll 4
  for (int c = 0; c < 128; ++c) {
    size_t idx = ((size_t)b * 128 + c) * 256 + n;
    float2 L = cl[idx];
    cin[idx] = make_float2(sr, si);
    float nr = lr * sr - li * si + L.x;
    float ni = lr * si + li * sr + L.y;
    sr = nr; si = ni;
  }
}

// ---------------------------------------------------------------------------
// K3f: f32 scan -> inner-real write + f32 states/u in LDS; pure-f32 VALU
// output GEMM out[32,256] = A[32,768] @ W2f  (A cols: 2n=Re s, 2n+1=Im s,
// 512+h=u). Thread o accumulates 32 rows.
// ---------------------------------------------------------------------------
__global__ __launch_bounds__(256, 1) void k3f(const float* __restrict__ in,
                                              float* BuRe,   // -> inner real
                                              float* BuIm,   // -> output
                                              const float2* __restrict__ cin,
                                              const float* __restrict__ lamre,
                                              const float* __restrict__ lamim,
                                              const float* __restrict__ W2f) {
  __shared__ float lAf[32 * 772];   // 98816 B; cols 0..511 states, 512..767 u
  int tid = threadIdx.x;
  int b = blockIdx.x >> 7, c = blockIdx.x & 127;
  size_t row0 = (size_t)b * 4096 + c * 32;

  // stage u (f32)
  #pragma unroll
  for (int pass = 0; pass < 8; ++pass) {
    int m = pass * 4 + (tid >> 6);
    int h0 = (tid & 63) * 4;
    *reinterpret_cast<float4*>(&lAf[m * 772 + 512 + h0]) =
        *reinterpret_cast<const float4*>(in + (row0 + m) * 256 + h0);
  }

  // f32 scan; thread = n
  {
    int n = tid;
    float2 s0 = cin[((size_t)b * 128 + c) * 256 + n];
    float sr = s0.x, si = s0.y;
    float lr = lamre[n], li = lamim[n];
    #pragma unroll 4
    for (int j = 0; j < 32; ++j) {
      size_t idx = (row0 + j) * 256 + n;
      float br = BuRe[idx];
      float bi = BuIm[idx];
      BuRe[idx] = sr;                      // inner real (pre-state)
      *reinterpret_cast<float2*>(&lAf[j * 772 + 2 * n]) = make_float2(sr, si);
      float nr = lr * sr - li * si + br;
      float ni = lr * si + li * sr + bi;
      sr = nr; si = ni;
    }
  }
  __syncthreads();

  // f32 VALU GEMM: thread o, 32 row-accumulators, LDS-broadcast A reads
  int o = tid;
  float acc[32];
  #pragma unroll
  for (int m = 0; m < 32; ++m) acc[m] = 0.f;

  for (int k = 0; k < 768; k += 4) {
    float w[4];
    #pragma unroll
    for (int i = 0; i < 4; ++i) w[i] = W2f[(k + i) * 256 + o];
    #pragma unroll
    for (int m = 0; m < 32; ++m) {
      float4 a4 = *reinterpret_cast<const float4*>(&lAf[m * 772 + k]);
      acc[m] += a4.x * w[0] + a4.y * w[1] + a4.z * w[2] + a4.w * w[3];
    }
  }

  #pragma unroll
  for (int m = 0; m < 32; ++m)
    BuIm[(row0 + m) * 256 + o] = acc[m];   // same thread (o==n) read these rows
}

// ---------------------------------------------------------------------------
extern "C" void kernel_launch(void* const* d_in, const int* in_sizes, int n_in,
                              void* d_out, int out_size, void* d_ws, size_t ws_size,
                              hipStream_t stream) {
  (void)in_sizes; (void)n_in; (void)out_size;
  const float* in       = (const float*)d_in[0];
  const float* nu_log   = (const float*)d_in[1];
  const float* theta_log= (const float*)d_in[2];
  const float* gamma_log= (const float*)d_in[3];
  const float* B_re     = (const float*)d_in[4];
  const float* B_im     = (const float*)d_in[5];
  const float* C_re     = (const float*)d_in[6];
  const float* C_im     = (const float*)d_in[7];
  const float* Dm       = (const float*)d_in[8];

  // ws: W1fre 256K | W1fim 256K | W2f 768K | lam | cl@2MB 4MB | cin@6MB 4MB = 10MB
  if (ws_size < (size_t)10 * 1024 * 1024) return;
  char* ws = (char*)d_ws;
  float* W1fre = (float*)(ws + 0);
  float* W1fim = (float*)(ws + 262144);
  float* W2f   = (float*)(ws + 524288);
  float* lamre  = (float*)(ws + 1310720);
  float* lamim  = lamre + 256;
  float* lamLre = lamre + 512;
  float* lamLim = lamre + 768;
  float2* cl  = (float2*)(ws + (size_t)2 * 1024 * 1024);
  float2* cin = (float2*)(ws + (size_t)6 * 1024 * 1024);

  float* BuIm = (float*)d_out;                               // [0,64MB)  -> final output
  float* BuRe = (float*)d_out + (size_t)16777216;            // [64,128MB)-> final inner real

  k0f<<<1281, 256, 0, stream>>>(nu_log, theta_log, gamma_log, B_re, B_im, C_re, C_im, Dm,
                                W1fre, W1fim, W2f, lamre, lamim, lamLre, lamLim);
  k1f<<<2048, 256, 0, stream>>>(in, W1fre, W1fim, BuRe, BuIm);
  k2a_local<<<2048, 256, 0, stream>>>(BuRe, BuIm, lamre, lamim, cl);
  k2b_scan<<<16, 256, 0, stream>>>(cl, cin, lamLre, lamLim);
  k3f<<<2048, 256, 0, stream>>>(in, BuRe, BuIm, cin, lamre, lamim, W2f);
}

// Round 6
// 982.591 us; speedup vs baseline: 1.2901x; 1.2901x over previous
//
#include <hip/hip_runtime.h>

// BISECTION ROUND: K1 = MFMA-bf16 (r4 version, f32 Bu outputs);
// K3 = VALU-f32 (r5 green version). K0 produces bf16 W1 (tiled) + f32 W2f.
// d_out = [0,64MB) output f32 (BuIm plane) | [64,128MB) inner-real f32 (BuRe).

typedef float  f32x4 __attribute__((ext_vector_type(4)));
typedef short  s16x8 __attribute__((ext_vector_type(8)));

__device__ __forceinline__ unsigned short f2bf(float x) {
  unsigned int u = __builtin_bit_cast(unsigned int, x);
  u += 0x7FFFu + ((u >> 16) & 1u);            // round-to-nearest-even
  return (unsigned short)(u >> 16);
}
__device__ __forceinline__ f32x4 mfma16(s16x8 a, s16x8 b, f32x4 c) {
  return __builtin_amdgcn_mfma_f32_16x16x32_bf16(a, b, c, 0, 0, 0);
}

// ---------------------------------------------------------------------------
// K0: W1 bf16 tiled [(kk*512+np)*32+ki] (np<256: re row n; else im row n-256),
//     W2f f32 [k*256+o] (k<512: even->C_re[o][k/2], odd->-C_im[o][k/2];
//     k>=512 -> D[o][k-512]), lam arrays.
// ---------------------------------------------------------------------------
__global__ void k0_mix(const float* __restrict__ nu_log, const float* __restrict__ theta_log,
                       const float* __restrict__ gamma_log,
                       const float* __restrict__ B_re, const float* __restrict__ B_im,
                       const float* __restrict__ C_re, const float* __restrict__ C_im,
                       const float* __restrict__ Dm,
                       unsigned short* __restrict__ W1, float* __restrict__ W2f,
                       float* __restrict__ lamre, float* __restrict__ lamim,
                       float* __restrict__ lamLre, float* __restrict__ lamLim) {
  int idx = blockIdx.x * 256 + threadIdx.x;
  if (idx < 131072) {
    int ki = idx & 31; int np_ = (idx >> 5) & 511; int kk = idx >> 14;
    int k = kk * 32 + ki; int n = np_ & 255;
    float g = expf(gamma_log[n]);
    float v = (np_ < 256) ? B_re[n * 256 + k] : B_im[n * 256 + k];
    W1[idx] = f2bf(g * v);
  } else if (idx < 327680) {
    int j = idx - 131072;
    int k = j >> 8, o = j & 255;
    float v;
    if (k < 512) { int n = k >> 1; v = (k & 1) ? -C_im[o * 256 + n] : C_re[o * 256 + n]; }
    else         { v = Dm[o * 256 + (k - 512)]; }
    W2f[j] = v;
  } else if (idx < 327936) {
    int n = idx - 327680;
    float la = expf(-expf(nu_log[n]));
    float th = expf(theta_log[n]);
    float lr = la * cosf(th), li = la * sinf(th);
    lamre[n] = lr; lamim[n] = li;
    float r = lr, i = li;
    #pragma unroll
    for (int t = 0; t < 5; ++t) { float nr = r * r - i * i; float ni = 2.f * r * i; r = nr; i = ni; }
    lamLre[n] = r; lamLim[n] = i;
  }
}

// ---------------------------------------------------------------------------
// K1: Bu = input @ W1^T (bf16 MFMA, f32 outputs). r4 version, unchanged.
// ---------------------------------------------------------------------------
__global__ __launch_bounds__(256, 2) void k1_gemm_bu(const float* __restrict__ in,
                                                     const unsigned short* __restrict__ W1,
                                                     float* __restrict__ BuRe,
                                                     float* __restrict__ BuIm) {
  __shared__ unsigned short lA[64 * 264];
  __shared__ unsigned short lB[256 * 40];
  int tid = threadIdx.x;
  int bid = blockIdx.x;
  int nblk = bid & 1, mblk = bid >> 1;
  int M0 = mblk * 64, n0 = nblk * 128;
  int lane = tid & 63, wid = tid >> 6;
  int wm = wid >> 1, wn = wid & 1;

  #pragma unroll
  for (int pass = 0; pass < 16; ++pass) {
    int m = pass * 4 + (tid >> 6);
    int h0 = (tid & 63) * 4;
    float4 v = *reinterpret_cast<const float4*>(in + (size_t)(M0 + m) * 256 + h0);
    ushort4 s; s.x = f2bf(v.x); s.y = f2bf(v.y); s.z = f2bf(v.z); s.w = f2bf(v.w);
    *reinterpret_cast<ushort4*>(&lA[m * 264 + h0]) = s;
  }

  f32x4 acc[2][4][2];
  #pragma unroll
  for (int a = 0; a < 2; ++a)
    #pragma unroll
    for (int b = 0; b < 4; ++b)
      #pragma unroll
      for (int p = 0; p < 2; ++p) acc[a][b][p] = f32x4{0.f, 0.f, 0.f, 0.f};

  for (int kk = 0; kk < 8; ++kk) {
    __syncthreads();
    {
      const unsigned short* src_re = W1 + ((size_t)kk * 512 + n0) * 32;
      const unsigned short* src_im = W1 + ((size_t)kk * 512 + 256 + n0) * 32;
      #pragma unroll
      for (int half = 0; half < 2; ++half) {
        const unsigned short* src = half ? src_im : src_re;
        int rbase = half * 128;
        #pragma unroll
        for (int q = 0; q < 2; ++q) {
          int chunk = q * 256 + tid;
          int r = chunk >> 2, off = (chunk & 3) * 8;
          *reinterpret_cast<uint4*>(&lB[(rbase + r) * 40 + off]) =
              *reinterpret_cast<const uint4*>(src + r * 32 + off);
        }
      }
    }
    __syncthreads();
    s16x8 af[2];
    #pragma unroll
    for (int mt = 0; mt < 2; ++mt)
      af[mt] = *reinterpret_cast<const s16x8*>(
          &lA[(wm * 32 + mt * 16 + (lane & 15)) * 264 + kk * 32 + (lane >> 4) * 8]);
    #pragma unroll
    for (int nt = 0; nt < 4; ++nt) {
      #pragma unroll
      for (int p = 0; p < 2; ++p) {
        int r = p * 128 + wn * 64 + nt * 16 + (lane & 15);
        s16x8 bfr = *reinterpret_cast<const s16x8*>(&lB[r * 40 + (lane >> 4) * 8]);
        #pragma unroll
        for (int mt = 0; mt < 2; ++mt)
          acc[mt][nt][p] = mfma16(af[mt], bfr, acc[mt][nt][p]);
      }
    }
  }

  #pragma unroll
  for (int mt = 0; mt < 2; ++mt)
    #pragma unroll
    for (int nt = 0; nt < 4; ++nt)
      #pragma unroll
      for (int r = 0; r < 4; ++r) {
        int m = M0 + wm * 32 + mt * 16 + (lane >> 4) * 4 + r;
        int n = n0 + wn * 64 + nt * 16 + (lane & 15);
        BuRe[(size_t)m * 256 + n] = acc[mt][nt][0][r];
        BuIm[(size_t)m * 256 + n] = acc[mt][nt][1][r];
      }
}

// ---------------------------------------------------------------------------
// K2a: per-chunk local reduction (unchanged, f32).
// ---------------------------------------------------------------------------
__global__ void k2a_local(const float* __restrict__ BuRe, const float* __restrict__ BuIm,
                          const float* __restrict__ lamre, const float* __restrict__ lamim,
                          float2* __restrict__ cl) {
  int b = blockIdx.x >> 7, c = blockIdx.x & 127, n = threadIdx.x;
  size_t row0 = (size_t)b * 4096 + c * 32;
  float lr = lamre[n], li = lamim[n];
  float xr = 0.f, xi = 0.f;
  #pragma unroll 8
  for (int j = 0; j < 32; ++j) {
    size_t idx = (row0 + j) * 256 + n;
    float br = BuRe[idx], bi = BuIm[idx];
    float nr = lr * xr - li * xi + br;
    float ni = lr * xi + li * xr + bi;
    xr = nr; xi = ni;
  }
  cl[((size_t)b * 128 + c) * 256 + n] = make_float2(xr, xi);
}

// ---------------------------------------------------------------------------
// K2b: carry scan (unchanged).
// ---------------------------------------------------------------------------
__global__ void k2b_scan(const float2* __restrict__ cl, float2* __restrict__ cin,
                         const float* __restrict__ lamLre, const float* __restrict__ lamLim) {
  int b = blockIdx.x, n = threadIdx.x;
  float lr = lamLre[n], li = lamLim[n];
  float sr = 0.f, si = 0.f;
  #pragma unroll 4
  for (int c = 0; c < 128; ++c) {
    size_t idx = ((size_t)b * 128 + c) * 256 + n;
    float2 L = cl[idx];
    cin[idx] = make_float2(sr, si);
    float nr = lr * sr - li * si + L.x;
    float ni = lr * si + li * sr + L.y;
    sr = nr; si = ni;
  }
}

// ---------------------------------------------------------------------------
// K3f: f32 scan + pure-f32 VALU output GEMM (r5 green version, unchanged).
// ---------------------------------------------------------------------------
__global__ __launch_bounds__(256, 1) void k3f(const float* __restrict__ in,
                                              float* BuRe,   // -> inner real
                                              float* BuIm,   // -> output
                                              const float2* __restrict__ cin,
                                              const float* __restrict__ lamre,
                                              const float* __restrict__ lamim,
                                              const float* __restrict__ W2f) {
  __shared__ float lAf[32 * 772];   // cols 0..511 states (2n,2n+1), 512..767 u
  int tid = threadIdx.x;
  int b = blockIdx.x >> 7, c = blockIdx.x & 127;
  size_t row0 = (size_t)b * 4096 + c * 32;

  #pragma unroll
  for (int pass = 0; pass < 8; ++pass) {
    int m = pass * 4 + (tid >> 6);
    int h0 = (tid & 63) * 4;
    *reinterpret_cast<float4*>(&lAf[m * 772 + 512 + h0]) =
        *reinterpret_cast<const float4*>(in + (row0 + m) * 256 + h0);
  }

  {
    int n = tid;
    float2 s0 = cin[((size_t)b * 128 + c) * 256 + n];
    float sr = s0.x, si = s0.y;
    float lr = lamre[n], li = lamim[n];
    #pragma unroll 4
    for (int j = 0; j < 32; ++j) {
      size_t idx = (row0 + j) * 256 + n;
      float br = BuRe[idx];
      float bi = BuIm[idx];
      BuRe[idx] = sr;                      // inner real (pre-state)
      *reinterpret_cast<float2*>(&lAf[j * 772 + 2 * n]) = make_float2(sr, si);
      float nr = lr * sr - li * si + br;
      float ni = lr * si + li * sr + bi;
      sr = nr; si = ni;
    }
  }
  __syncthreads();

  int o = tid;
  float acc[32];
  #pragma unroll
  for (int m = 0; m < 32; ++m) acc[m] = 0.f;

  for (int k = 0; k < 768; k += 4) {
    float w[4];
    #pragma unroll
    for (int i = 0; i < 4; ++i) w[i] = W2f[(k + i) * 256 + o];
    #pragma unroll
    for (int m = 0; m < 32; ++m) {
      float4 a4 = *reinterpret_cast<const float4*>(&lAf[m * 772 + k]);
      acc[m] += a4.x * w[0] + a4.y * w[1] + a4.z * w[2] + a4.w * w[3];
    }
  }

  #pragma unroll
  for (int m = 0; m < 32; ++m)
    BuIm[(row0 + m) * 256 + o] = acc[m];
}

// ---------------------------------------------------------------------------
extern "C" void kernel_launch(void* const* d_in, const int* in_sizes, int n_in,
                              void* d_out, int out_size, void* d_ws, size_t ws_size,
                              hipStream_t stream) {
  (void)in_sizes; (void)n_in; (void)out_size;
  const float* in       = (const float*)d_in[0];
  const float* nu_log   = (const float*)d_in[1];
  const float* theta_log= (const float*)d_in[2];
  const float* gamma_log= (const float*)d_in[3];
  const float* B_re     = (const float*)d_in[4];
  const float* B_im     = (const float*)d_in[5];
  const float* C_re     = (const float*)d_in[6];
  const float* C_im     = (const float*)d_in[7];
  const float* Dm       = (const float*)d_in[8];

  // ws: W1 bf16 [0,256K) | W2f f32 [256K,1M) | lam @1M | cl @2MB | cin @6MB
  if (ws_size < (size_t)10 * 1024 * 1024) return;
  char* ws = (char*)d_ws;
  unsigned short* W1 = (unsigned short*)(ws + 0);
  float* W2f   = (float*)(ws + 262144);
  float* lamre  = (float*)(ws + 1048576);
  float* lamim  = lamre + 256;
  float* lamLre = lamre + 512;
  float* lamLim = lamre + 768;
  float2* cl  = (float2*)(ws + (size_t)2 * 1024 * 1024);
  float2* cin = (float2*)(ws + (size_t)6 * 1024 * 1024);

  float* BuIm = (float*)d_out;                               // [0,64MB)  -> final output
  float* BuRe = (float*)d_out + (size_t)16777216;            // [64,128MB)-> final inner real

  k0_mix<<<1281, 256, 0, stream>>>(nu_log, theta_log, gamma_log, B_re, B_im, C_re, C_im, Dm,
                                   W1, W2f, lamre, lamim, lamLre, lamLim);
  k1_gemm_bu<<<2048, 256, 0, stream>>>(in, W1, BuRe, BuIm);
  k2a_local<<<2048, 256, 0, stream>>>(BuRe, BuIm, lamre, lamim, cl);
  k2b_scan<<<16, 256, 0, stream>>>(cl, cin, lamLre, lamLim);
  k3f<<<2048, 256, 0, stream>>>(in, BuRe, BuIm, cin, lamre, lamim, W2f);
}

// Round 7
// 243.110 us; speedup vs baseline: 5.2141x; 4.0418x over previous
//
#include <hip/hip_runtime.h>

// LRU pipeline, round 7: split K3 into pure-scan (k3a) + K1-clone MFMA GEMM (k3b).
// d_out = [0,64MB) output f32 | [64,128MB) inner-real f32.
// Region lifecycle:
//   BuRe region [64,128MB): K1 writes Bu_re f32 -> k2a reads -> k3a reads then
//     overwrites per-thread with inner-real f32 (FINAL output 1).
//   BuIm region [0,64MB):  K1 writes Bu_im f32 -> k2a reads -> k3a reads then
//     overwrites per-thread with packed bf16 states (re|im in u32) -> k3b reads
//     rows (staging, before barriers) then epilogue overwrites same rows with
//     the final output f32 (FINAL output 0).

typedef float  f32x4 __attribute__((ext_vector_type(4)));
typedef short  s16x8 __attribute__((ext_vector_type(8)));

__device__ __forceinline__ unsigned short f2bf(float x) {
  unsigned int u = __builtin_bit_cast(unsigned int, x);
  u += 0x7FFFu + ((u >> 16) & 1u);            // round-to-nearest-even
  return (unsigned short)(u >> 16);
}
__device__ __forceinline__ f32x4 mfma16(s16x8 a, s16x8 b, f32x4 c) {
  return __builtin_amdgcn_mfma_f32_16x16x32_bf16(a, b, c, 0, 0, 0);
}

// ---------------------------------------------------------------------------
// K0: W1 bf16 tiled (green via K1) + W2f f32 [k*256+o] (green via r6 k3f) + lam.
// ---------------------------------------------------------------------------
__global__ void k0_mix(const float* __restrict__ nu_log, const float* __restrict__ theta_log,
                       const float* __restrict__ gamma_log,
                       const float* __restrict__ B_re, const float* __restrict__ B_im,
                       const float* __restrict__ C_re, const float* __restrict__ C_im,
                       const float* __restrict__ Dm,
                       unsigned short* __restrict__ W1, float* __restrict__ W2f,
                       float* __restrict__ lamre, float* __restrict__ lamim,
                       float* __restrict__ lamLre, float* __restrict__ lamLim) {
  int idx = blockIdx.x * 256 + threadIdx.x;
  if (idx < 131072) {
    int ki = idx & 31; int np_ = (idx >> 5) & 511; int kk = idx >> 14;
    int k = kk * 32 + ki; int n = np_ & 255;
    float g = expf(gamma_log[n]);
    float v = (np_ < 256) ? B_re[n * 256 + k] : B_im[n * 256 + k];
    W1[idx] = f2bf(g * v);
  } else if (idx < 327680) {
    int j = idx - 131072;
    int k = j >> 8, o = j & 255;
    float v;
    if (k < 512) { int n = k >> 1; v = (k & 1) ? -C_im[o * 256 + n] : C_re[o * 256 + n]; }
    else         { v = Dm[o * 256 + (k - 512)]; }
    W2f[j] = v;
  } else if (idx < 327936) {
    int n = idx - 327680;
    float la = expf(-expf(nu_log[n]));
    float th = expf(theta_log[n]);
    float lr = la * cosf(th), li = la * sinf(th);
    lamre[n] = lr; lamim[n] = li;
    float r = lr, i = li;
    #pragma unroll
    for (int t = 0; t < 5; ++t) { float nr = r * r - i * i; float ni = 2.f * r * i; r = nr; i = ni; }
    lamLre[n] = r; lamLim[n] = i;
  }
}

// ---------------------------------------------------------------------------
// K0b: tile green W2f into bf16 W2t[(kk*256+o)*32+ki] = bf16(W2f[(kk*32+ki)*256+o]).
// ---------------------------------------------------------------------------
__global__ void k0b_tile(const float* __restrict__ W2f, unsigned short* __restrict__ W2t) {
  int j = blockIdx.x * 256 + threadIdx.x;          // [0,196608)
  int ki = j & 31, o = (j >> 5) & 255, kk = j >> 13;
  W2t[j] = f2bf(W2f[(kk * 32 + ki) * 256 + o]);
}

// ---------------------------------------------------------------------------
// K1: Bu = input @ W1^T (bf16 MFMA, f32 plane outputs). GREEN, unchanged.
// ---------------------------------------------------------------------------
__global__ __launch_bounds__(256, 2) void k1_gemm_bu(const float* __restrict__ in,
                                                     const unsigned short* __restrict__ W1,
                                                     float* __restrict__ BuRe,
                                                     float* __restrict__ BuIm) {
  __shared__ unsigned short lA[64 * 264];
  __shared__ unsigned short lB[256 * 40];
  int tid = threadIdx.x;
  int bid = blockIdx.x;
  int nblk = bid & 1, mblk = bid >> 1;
  int M0 = mblk * 64, n0 = nblk * 128;
  int lane = tid & 63, wid = tid >> 6;
  int wm = wid >> 1, wn = wid & 1;

  #pragma unroll
  for (int pass = 0; pass < 16; ++pass) {
    int m = pass * 4 + (tid >> 6);
    int h0 = (tid & 63) * 4;
    float4 v = *reinterpret_cast<const float4*>(in + (size_t)(M0 + m) * 256 + h0);
    ushort4 s; s.x = f2bf(v.x); s.y = f2bf(v.y); s.z = f2bf(v.z); s.w = f2bf(v.w);
    *reinterpret_cast<ushort4*>(&lA[m * 264 + h0]) = s;
  }

  f32x4 acc[2][4][2];
  #pragma unroll
  for (int a = 0; a < 2; ++a)
    #pragma unroll
    for (int b = 0; b < 4; ++b)
      #pragma unroll
      for (int p = 0; p < 2; ++p) acc[a][b][p] = f32x4{0.f, 0.f, 0.f, 0.f};

  for (int kk = 0; kk < 8; ++kk) {
    __syncthreads();
    {
      const unsigned short* src_re = W1 + ((size_t)kk * 512 + n0) * 32;
      const unsigned short* src_im = W1 + ((size_t)kk * 512 + 256 + n0) * 32;
      #pragma unroll
      for (int half = 0; half < 2; ++half) {
        const unsigned short* src = half ? src_im : src_re;
        int rbase = half * 128;
        #pragma unroll
        for (int q = 0; q < 2; ++q) {
          int chunk = q * 256 + tid;
          int r = chunk >> 2, off = (chunk & 3) * 8;
          *reinterpret_cast<uint4*>(&lB[(rbase + r) * 40 + off]) =
              *reinterpret_cast<const uint4*>(src + r * 32 + off);
        }
      }
    }
    __syncthreads();
    s16x8 af[2];
    #pragma unroll
    for (int mt = 0; mt < 2; ++mt)
      af[mt] = *reinterpret_cast<const s16x8*>(
          &lA[(wm * 32 + mt * 16 + (lane & 15)) * 264 + kk * 32 + (lane >> 4) * 8]);
    #pragma unroll
    for (int nt = 0; nt < 4; ++nt) {
      #pragma unroll
      for (int p = 0; p < 2; ++p) {
        int r = p * 128 + wn * 64 + nt * 16 + (lane & 15);
        s16x8 bfr = *reinterpret_cast<const s16x8*>(&lB[r * 40 + (lane >> 4) * 8]);
        #pragma unroll
        for (int mt = 0; mt < 2; ++mt)
          acc[mt][nt][p] = mfma16(af[mt], bfr, acc[mt][nt][p]);
      }
    }
  }

  #pragma unroll
  for (int mt = 0; mt < 2; ++mt)
    #pragma unroll
    for (int nt = 0; nt < 4; ++nt)
      #pragma unroll
      for (int r = 0; r < 4; ++r) {
        int m = M0 + wm * 32 + mt * 16 + (lane >> 4) * 4 + r;
        int n = n0 + wn * 64 + nt * 16 + (lane & 15);
        BuRe[(size_t)m * 256 + n] = acc[mt][nt][0][r];
        BuIm[(size_t)m * 256 + n] = acc[mt][nt][1][r];
      }
}

// ---------------------------------------------------------------------------
// K2a: per-chunk local reduction (green, unchanged).
// ---------------------------------------------------------------------------
__global__ void k2a_local(const float* __restrict__ BuRe, const float* __restrict__ BuIm,
                          const float* __restrict__ lamre, const float* __restrict__ lamim,
                          float2* __restrict__ cl) {
  int b = blockIdx.x >> 7, c = blockIdx.x & 127, n = threadIdx.x;
  size_t row0 = (size_t)b * 4096 + c * 32;
  float lr = lamre[n], li = lamim[n];
  float xr = 0.f, xi = 0.f;
  #pragma unroll 8
  for (int j = 0; j < 32; ++j) {
    size_t idx = (row0 + j) * 256 + n;
    float br = BuRe[idx], bi = BuIm[idx];
    float nr = lr * xr - li * xi + br;
    float ni = lr * xi + li * xr + bi;
    xr = nr; xi = ni;
  }
  cl[((size_t)b * 128 + c) * 256 + n] = make_float2(xr, xi);
}

// ---------------------------------------------------------------------------
// K2b: carry scan (green, unchanged).
// ---------------------------------------------------------------------------
__global__ void k2b_scan(const float2* __restrict__ cl, float2* __restrict__ cin,
                         const float* __restrict__ lamLre, const float* __restrict__ lamLim) {
  int b = blockIdx.x, n = threadIdx.x;
  float lr = lamLre[n], li = lamLim[n];
  float sr = 0.f, si = 0.f;
  #pragma unroll 4
  for (int c = 0; c < 128; ++c) {
    size_t idx = ((size_t)b * 128 + c) * 256 + n;
    float2 L = cl[idx];
    cin[idx] = make_float2(sr, si);
    float nr = lr * sr - li * si + L.x;
    float ni = lr * si + li * sr + L.y;
    sr = nr; si = ni;
  }
}

// ---------------------------------------------------------------------------
// K3a: pure f32 scan (green r6 scan code). Thread n, chunk (b,c).
// BuRe[idx]: read Bu_re -> overwrite with inner-real f32 (exact, final).
// BuImU[idx]: read Bu_im f32 (bitcast) -> overwrite with packed bf16 (re|im).
// ---------------------------------------------------------------------------
__global__ __launch_bounds__(256) void k3a_scan(float* BuRe, unsigned int* BuImU,
                                                const float2* __restrict__ cin,
                                                const float* __restrict__ lamre,
                                                const float* __restrict__ lamim) {
  int b = blockIdx.x >> 7, c = blockIdx.x & 127, n = threadIdx.x;
  size_t row0 = (size_t)b * 4096 + c * 32;
  float2 s0 = cin[((size_t)b * 128 + c) * 256 + n];
  float sr = s0.x, si = s0.y;
  float lr = lamre[n], li = lamim[n];
  #pragma unroll 4
  for (int j = 0; j < 32; ++j) {
    size_t idx = (row0 + j) * 256 + n;
    float br = BuRe[idx];
    float bi = __builtin_bit_cast(float, BuImU[idx]);
    BuRe[idx] = sr;                                     // inner real (pre-state), f32 exact
    BuImU[idx] = (unsigned int)f2bf(sr) | ((unsigned int)f2bf(si) << 16);
    float nr = lr * sr - li * si + br;
    float ni = lr * si + li * sr + bi;
    sr = nr; si = ni;
  }
}

// ---------------------------------------------------------------------------
// K3b: K1-clone MFMA GEMM. out[32,256] = A[32,768] @ W2t^T per chunk.
// A cols 0..511 = packed states from SPack (BuIm region, already bf16),
// A cols 512..767 = u from `in` (f32 -> bf16, K1's staging pattern).
// 4 waves as 2(M:16 rows) x 2(N:128 cols). Epilogue overwrites own SPack rows
// with the final output (all SPack reads drain before first barrier).
// ---------------------------------------------------------------------------
__global__ __launch_bounds__(256, 2) void k3b_gemm(const float* __restrict__ in,
                                                   const unsigned short* SPack,
                                                   const unsigned short* __restrict__ W2t,
                                                   float* outp) {
  __shared__ unsigned short lA[32 * 776];   // 49664 B
  __shared__ unsigned short lB[256 * 40];   // 20480 B
  int tid = threadIdx.x, lane = tid & 63, wid = tid >> 6;
  int wm = wid >> 1, wn = wid & 1;
  size_t row0 = (size_t)blockIdx.x * 32;

  // stage A cols 0..511: packed bf16 states, 32 rows x 512 shorts
  #pragma unroll
  for (int i = 0; i < 8; ++i) {
    int chunk = i * 256 + tid;               // [0,2048) chunks of 8 shorts
    int r = chunk >> 6;
    int off = (chunk & 63) * 8;
    *reinterpret_cast<uint4*>(&lA[r * 776 + off]) =
        *reinterpret_cast<const uint4*>(SPack + (row0 + r) * 512 + off);
  }
  // stage A cols 512..767: u f32 -> bf16 (K1 pattern)
  #pragma unroll
  for (int pass = 0; pass < 8; ++pass) {
    int m = pass * 4 + (tid >> 6);
    int h0 = (tid & 63) * 4;
    float4 v = *reinterpret_cast<const float4*>(in + (row0 + m) * 256 + h0);
    ushort4 s; s.x = f2bf(v.x); s.y = f2bf(v.y); s.z = f2bf(v.z); s.w = f2bf(v.w);
    *reinterpret_cast<ushort4*>(&lA[m * 776 + 512 + h0]) = s;
  }

  f32x4 acc[8];
  #pragma unroll
  for (int nt = 0; nt < 8; ++nt) acc[nt] = f32x4{0.f, 0.f, 0.f, 0.f};

  for (int kk = 0; kk < 24; ++kk) {
    __syncthreads();
    const unsigned short* src = W2t + (size_t)kk * 8192;
    #pragma unroll
    for (int q = 0; q < 4; ++q) {
      int chunk = q * 256 + tid;
      int o = chunk >> 2, off = (chunk & 3) * 8;
      *reinterpret_cast<uint4*>(&lB[o * 40 + off]) =
          *reinterpret_cast<const uint4*>(src + o * 32 + off);
    }
    __syncthreads();
    s16x8 af = *reinterpret_cast<const s16x8*>(
        &lA[(wm * 16 + (lane & 15)) * 776 + kk * 32 + (lane >> 4) * 8]);
    #pragma unroll
    for (int nt = 0; nt < 8; ++nt) {
      int o = wn * 128 + nt * 16 + (lane & 15);
      s16x8 bfr = *reinterpret_cast<const s16x8*>(&lB[o * 40 + (lane >> 4) * 8]);
      acc[nt] = mfma16(af, bfr, acc[nt]);
    }
  }

  #pragma unroll
  for (int nt = 0; nt < 8; ++nt)
    #pragma unroll
    for (int r = 0; r < 4; ++r) {
      size_t row = row0 + wm * 16 + (lane >> 4) * 4 + r;
      int col = wn * 128 + nt * 16 + (lane & 15);
      outp[row * 256 + col] = acc[nt][r];
    }
}

// ---------------------------------------------------------------------------
extern "C" void kernel_launch(void* const* d_in, const int* in_sizes, int n_in,
                              void* d_out, int out_size, void* d_ws, size_t ws_size,
                              hipStream_t stream) {
  (void)in_sizes; (void)n_in; (void)out_size;
  const float* in       = (const float*)d_in[0];
  const float* nu_log   = (const float*)d_in[1];
  const float* theta_log= (const float*)d_in[2];
  const float* gamma_log= (const float*)d_in[3];
  const float* B_re     = (const float*)d_in[4];
  const float* B_im     = (const float*)d_in[5];
  const float* C_re     = (const float*)d_in[6];
  const float* C_im     = (const float*)d_in[7];
  const float* Dm       = (const float*)d_in[8];

  // ws: W1 [0,256K) | W2f [256K,1M) | lam @1M | W2t @1.25M (384K) | cl @2M (4M) | cin @6M (4M)
  if (ws_size < (size_t)10 * 1024 * 1024) return;
  char* ws = (char*)d_ws;
  unsigned short* W1 = (unsigned short*)(ws + 0);
  float* W2f   = (float*)(ws + 262144);
  float* lamre  = (float*)(ws + 1048576);
  float* lamim  = lamre + 256;
  float* lamLre = lamre + 512;
  float* lamLim = lamre + 768;
  unsigned short* W2t = (unsigned short*)(ws + 1310720);
  float2* cl  = (float2*)(ws + (size_t)2 * 1024 * 1024);
  float2* cin = (float2*)(ws + (size_t)6 * 1024 * 1024);

  float* BuIm = (float*)d_out;                               // [0,64MB)  -> final output
  float* BuRe = (float*)d_out + (size_t)16777216;            // [64,128MB)-> final inner real

  k0_mix<<<1281, 256, 0, stream>>>(nu_log, theta_log, gamma_log, B_re, B_im, C_re, C_im, Dm,
                                   W1, W2f, lamre, lamim, lamLre, lamLim);
  k0b_tile<<<768, 256, 0, stream>>>(W2f, W2t);
  k1_gemm_bu<<<2048, 256, 0, stream>>>(in, W1, BuRe, BuIm);
  k2a_local<<<2048, 256, 0, stream>>>(BuRe, BuIm, lamre, lamim, cl);
  k2b_scan<<<16, 256, 0, stream>>>(cl, cin, lamLre, lamLim);
  k3a_scan<<<2048, 256, 0, stream>>>(BuRe, (unsigned int*)BuIm, cin, lamre, lamim);
  k3b_gemm<<<2048, 256, 0, stream>>>(in, (const unsigned short*)BuIm, W2t, BuIm);
}

// Round 8
// 228.199 us; speedup vs baseline: 5.5548x; 1.0653x over previous
//
#include <hip/hip_runtime.h>

// LRU r8: packed-bf16 Bu + prefetch/double-buffered GEMMs.
// d_out = [0,64MB) output f32 | [64,128MB) inner-real f32.
// Region lifecycle:
//   [0,64MB):  k1 writes packed Bu (bf16 re|im in u32) -> k2a reads -> k3a reads
//              then overwrites per-thread with packed bf16 states -> k3b stages
//              rows (before barriers) then epilogue overwrites with output f32.
//   [64,128MB): untouched until k3a writes inner-real f32 (exact, final).

typedef float  f32x4 __attribute__((ext_vector_type(4)));
typedef short  s16x8 __attribute__((ext_vector_type(8)));

__device__ __forceinline__ unsigned short f2bf(float x) {
  unsigned int u = __builtin_bit_cast(unsigned int, x);
  u += 0x7FFFu + ((u >> 16) & 1u);            // round-to-nearest-even
  return (unsigned short)(u >> 16);
}
__device__ __forceinline__ float bf2f(unsigned int s) {
  unsigned int u = s << 16;
  return __builtin_bit_cast(float, u);
}
__device__ __forceinline__ f32x4 mfma16(s16x8 a, s16x8 b, f32x4 c) {
  return __builtin_amdgcn_mfma_f32_16x16x32_bf16(a, b, c, 0, 0, 0);
}

// ---------------------------------------------------------------------------
// K0: W1 bf16 tiled + W2f f32 [k*256+o] + lam arrays (green, unchanged).
// ---------------------------------------------------------------------------
__global__ void k0_mix(const float* __restrict__ nu_log, const float* __restrict__ theta_log,
                       const float* __restrict__ gamma_log,
                       const float* __restrict__ B_re, const float* __restrict__ B_im,
                       const float* __restrict__ C_re, const float* __restrict__ C_im,
                       const float* __restrict__ Dm,
                       unsigned short* __restrict__ W1, float* __restrict__ W2f,
                       float* __restrict__ lamre, float* __restrict__ lamim,
                       float* __restrict__ lamLre, float* __restrict__ lamLim) {
  int idx = blockIdx.x * 256 + threadIdx.x;
  if (idx < 131072) {
    int ki = idx & 31; int np_ = (idx >> 5) & 511; int kk = idx >> 14;
    int k = kk * 32 + ki; int n = np_ & 255;
    float g = expf(gamma_log[n]);
    float v = (np_ < 256) ? B_re[n * 256 + k] : B_im[n * 256 + k];
    W1[idx] = f2bf(g * v);
  } else if (idx < 327680) {
    int j = idx - 131072;
    int k = j >> 8, o = j & 255;
    float v;
    if (k < 512) { int n = k >> 1; v = (k & 1) ? -C_im[o * 256 + n] : C_re[o * 256 + n]; }
    else         { v = Dm[o * 256 + (k - 512)]; }
    W2f[j] = v;
  } else if (idx < 327936) {
    int n = idx - 327680;
    float la = expf(-expf(nu_log[n]));
    float th = expf(theta_log[n]);
    float lr = la * cosf(th), li = la * sinf(th);
    lamre[n] = lr; lamim[n] = li;
    float r = lr, i = li;
    #pragma unroll
    for (int t = 0; t < 5; ++t) { float nr = r * r - i * i; float ni = 2.f * r * i; r = nr; i = ni; }
    lamLre[n] = r; lamLim[n] = i;
  }
}

// ---------------------------------------------------------------------------
// K0b: tile W2f into bf16 W2t[(kk*256+o)*32+ki] (green, unchanged).
// ---------------------------------------------------------------------------
__global__ void k0b_tile(const float* __restrict__ W2f, unsigned short* __restrict__ W2t) {
  int j = blockIdx.x * 256 + threadIdx.x;          // [0,196608)
  int ki = j & 31, o = (j >> 5) & 255, kk = j >> 13;
  W2t[j] = f2bf(W2f[(kk * 32 + ki) * 256 + o]);
}

// ---------------------------------------------------------------------------
// K1: Bu = input @ W1^T (bf16 MFMA). Packed u32 output. Double-buffered lB,
// register-prefetch, ONE barrier per K-step.
// ---------------------------------------------------------------------------
__global__ __launch_bounds__(256, 2) void k1_gemm_bu(const float* __restrict__ in,
                                                     const unsigned short* __restrict__ W1,
                                                     unsigned int* __restrict__ BuP) {
  __shared__ unsigned short lA[64 * 264];         // 33792 B
  __shared__ unsigned short lB[2][256 * 40];      // 2 x 20480 B
  int tid = threadIdx.x;
  int bid = blockIdx.x;
  int nblk = bid & 1, mblk = bid >> 1;
  int M0 = mblk * 64, n0 = nblk * 128;
  int lane = tid & 63, wid = tid >> 6;
  int wm = wid >> 1, wn = wid & 1;

  // stage A: 64 rows x 256 f32 -> bf16 LDS
  #pragma unroll
  for (int pass = 0; pass < 16; ++pass) {
    int m = pass * 4 + (tid >> 6);
    int h0 = (tid & 63) * 4;
    float4 v = *reinterpret_cast<const float4*>(in + (size_t)(M0 + m) * 256 + h0);
    ushort4 s; s.x = f2bf(v.x); s.y = f2bf(v.y); s.z = f2bf(v.z); s.w = f2bf(v.w);
    *reinterpret_cast<ushort4*>(&lA[m * 264 + h0]) = s;
  }

  uint4 pre[4];
  auto loadB = [&](int kk) {
    const unsigned short* src_re = W1 + ((size_t)kk * 512 + n0) * 32;
    const unsigned short* src_im = W1 + ((size_t)kk * 512 + 256 + n0) * 32;
    #pragma unroll
    for (int half = 0; half < 2; ++half) {
      const unsigned short* src = half ? src_im : src_re;
      #pragma unroll
      for (int q = 0; q < 2; ++q) {
        int chunk = q * 256 + tid;
        int r = chunk >> 2, off = (chunk & 3) * 8;
        pre[half * 2 + q] = *reinterpret_cast<const uint4*>(src + r * 32 + off);
      }
    }
  };
  auto writeB = [&](int buf) {
    #pragma unroll
    for (int half = 0; half < 2; ++half)
      #pragma unroll
      for (int q = 0; q < 2; ++q) {
        int chunk = q * 256 + tid;
        int r = chunk >> 2, off = (chunk & 3) * 8;
        *reinterpret_cast<uint4*>(&lB[buf][(half * 128 + r) * 40 + off]) = pre[half * 2 + q];
      }
  };

  loadB(0); writeB(0); loadB(1);
  __syncthreads();

  f32x4 acc[2][4][2];
  #pragma unroll
  for (int a = 0; a < 2; ++a)
    #pragma unroll
    for (int b = 0; b < 4; ++b)
      #pragma unroll
      for (int p = 0; p < 2; ++p) acc[a][b][p] = f32x4{0.f, 0.f, 0.f, 0.f};

  for (int kk = 0; kk < 8; ++kk) {
    int cur = kk & 1;
    s16x8 af[2];
    #pragma unroll
    for (int mt = 0; mt < 2; ++mt)
      af[mt] = *reinterpret_cast<const s16x8*>(
          &lA[(wm * 32 + mt * 16 + (lane & 15)) * 264 + kk * 32 + (lane >> 4) * 8]);
    #pragma unroll
    for (int nt = 0; nt < 4; ++nt) {
      #pragma unroll
      for (int p = 0; p < 2; ++p) {
        int r = p * 128 + wn * 64 + nt * 16 + (lane & 15);
        s16x8 bfr = *reinterpret_cast<const s16x8*>(&lB[cur][r * 40 + (lane >> 4) * 8]);
        #pragma unroll
        for (int mt = 0; mt < 2; ++mt)
          acc[mt][nt][p] = mfma16(af[mt], bfr, acc[mt][nt][p]);
      }
    }
    if (kk < 7) { writeB(cur ^ 1); if (kk < 6) loadB(kk + 2); }
    __syncthreads();
  }

  // epilogue: pack (re,im) bf16 pairs
  #pragma unroll
  for (int mt = 0; mt < 2; ++mt)
    #pragma unroll
    for (int nt = 0; nt < 4; ++nt)
      #pragma unroll
      for (int r = 0; r < 4; ++r) {
        int m = M0 + wm * 32 + mt * 16 + (lane >> 4) * 4 + r;
        int n = n0 + wn * 64 + nt * 16 + (lane & 15);
        unsigned int pk = (unsigned int)f2bf(acc[mt][nt][0][r]) |
                          ((unsigned int)f2bf(acc[mt][nt][1][r]) << 16);
        BuP[(size_t)m * 256 + n] = pk;
      }
}

// ---------------------------------------------------------------------------
// K2a: per-chunk local reduction from packed Bu.
// ---------------------------------------------------------------------------
__global__ void k2a_local(const unsigned int* __restrict__ BuP,
                          const float* __restrict__ lamre, const float* __restrict__ lamim,
                          float2* __restrict__ cl) {
  int b = blockIdx.x >> 7, c = blockIdx.x & 127, n = threadIdx.x;
  size_t row0 = (size_t)b * 4096 + c * 32;
  float lr = lamre[n], li = lamim[n];
  float xr = 0.f, xi = 0.f;
  #pragma unroll 8
  for (int j = 0; j < 32; ++j) {
    unsigned int v = BuP[(row0 + j) * 256 + n];
    float br = bf2f(v & 0xffffu), bi = bf2f(v >> 16);
    float nr = lr * xr - li * xi + br;
    float ni = lr * xi + li * xr + bi;
    xr = nr; xi = ni;
  }
  cl[((size_t)b * 128 + c) * 256 + n] = make_float2(xr, xi);
}

// ---------------------------------------------------------------------------
// K2b: carry scan (green, unchanged).
// ---------------------------------------------------------------------------
__global__ void k2b_scan(const float2* __restrict__ cl, float2* __restrict__ cin,
                         const float* __restrict__ lamLre, const float* __restrict__ lamLim) {
  int b = blockIdx.x, n = threadIdx.x;
  float lr = lamLre[n], li = lamLim[n];
  float sr = 0.f, si = 0.f;
  #pragma unroll 4
  for (int c = 0; c < 128; ++c) {
    size_t idx = ((size_t)b * 128 + c) * 256 + n;
    float2 L = cl[idx];
    cin[idx] = make_float2(sr, si);
    float nr = lr * sr - li * si + L.x;
    float ni = lr * si + li * sr + L.y;
    sr = nr; si = ni;
  }
}

// ---------------------------------------------------------------------------
// K3a: f32 scan. Reads packed Bu, overwrites with packed bf16 states (same
// thread, same idx), writes inner-real f32 exact to the second region.
// ---------------------------------------------------------------------------
__global__ __launch_bounds__(256) void k3a_scan(unsigned int* BuP, float* __restrict__ innerRe,
                                                const float2* __restrict__ cin,
                                                const float* __restrict__ lamre,
                                                const float* __restrict__ lamim) {
  int b = blockIdx.x >> 7, c = blockIdx.x & 127, n = threadIdx.x;
  size_t row0 = (size_t)b * 4096 + c * 32;
  float2 s0 = cin[((size_t)b * 128 + c) * 256 + n];
  float sr = s0.x, si = s0.y;
  float lr = lamre[n], li = lamim[n];
  #pragma unroll 4
  for (int j = 0; j < 32; ++j) {
    size_t idx = (row0 + j) * 256 + n;
    unsigned int v = BuP[idx];                          // read Bu FIRST
    BuP[idx] = (unsigned int)f2bf(sr) | ((unsigned int)f2bf(si) << 16);
    innerRe[idx] = sr;                                  // inner real (pre-state)
    float br = bf2f(v & 0xffffu), bi = bf2f(v >> 16);
    float nr = lr * sr - li * si + br;
    float ni = lr * si + li * sr + bi;
    sr = nr; si = ni;
  }
}

// ---------------------------------------------------------------------------
// K3b: output GEMM, M=64 per block, 512 threads (8 waves: 4M x 2N).
// Double-buffered lB (stride 32, linear copy), register-prefetch, one barrier
// per K-step. A cols 0..511 from SPack (packed states), 512..767 from `in`.
// Epilogue overwrites this block's SPack rows with the final output.
// ---------------------------------------------------------------------------
__global__ __launch_bounds__(512, 2) void k3b_gemm(const float* __restrict__ in,
                                                   const unsigned short* SPack,
                                                   const unsigned short* __restrict__ W2t,
                                                   float* outp) {
  __shared__ unsigned short lA[64 * 776];         // 99328 B
  __shared__ unsigned short lB[2][256 * 32];      // 2 x 16384 B
  int tid = threadIdx.x, lane = tid & 63, wid = tid >> 6;
  int wm = wid >> 1, wn = wid & 1;                 // 4 M-waves x 2 N-waves
  size_t row0 = (size_t)blockIdx.x * 64;

  // stage A cols 0..511: packed bf16 states (64 rows x 512 shorts)
  #pragma unroll
  for (int i = 0; i < 8; ++i) {
    int chunk = i * 512 + tid;                     // [0,4096) chunks of 8 shorts
    int r = chunk >> 6, c8 = (chunk & 63) * 8;
    *reinterpret_cast<uint4*>(&lA[r * 776 + c8]) =
        *reinterpret_cast<const uint4*>(SPack + (row0 + r) * 512 + c8);
  }
  // stage A cols 512..767: u f32 -> bf16
  #pragma unroll
  for (int pass = 0; pass < 8; ++pass) {
    int m = pass * 8 + (tid >> 6);
    int h0 = (tid & 63) * 4;
    float4 v = *reinterpret_cast<const float4*>(in + (row0 + m) * 256 + h0);
    ushort4 s; s.x = f2bf(v.x); s.y = f2bf(v.y); s.z = f2bf(v.z); s.w = f2bf(v.w);
    *reinterpret_cast<ushort4*>(&lA[m * 776 + 512 + h0]) = s;
  }

  uint4 pre[2];
  auto loadB = [&](int kk) {
    #pragma unroll
    for (int q = 0; q < 2; ++q)
      pre[q] = *reinterpret_cast<const uint4*>(W2t + (size_t)kk * 8192 + (q * 512 + tid) * 8);
  };
  auto writeB = [&](int buf) {
    #pragma unroll
    for (int q = 0; q < 2; ++q)
      *reinterpret_cast<uint4*>(&lB[buf][(q * 512 + tid) * 8]) = pre[q];
  };

  loadB(0); writeB(0); loadB(1);
  __syncthreads();

  f32x4 acc[8];
  #pragma unroll
  for (int nt = 0; nt < 8; ++nt) acc[nt] = f32x4{0.f, 0.f, 0.f, 0.f};

  for (int kk = 0; kk < 24; ++kk) {
    int cur = kk & 1;
    s16x8 af = *reinterpret_cast<const s16x8*>(
        &lA[(wm * 16 + (lane & 15)) * 776 + kk * 32 + (lane >> 4) * 8]);
    #pragma unroll
    for (int nt = 0; nt < 8; ++nt) {
      int o = wn * 128 + nt * 16 + (lane & 15);
      s16x8 bfr = *reinterpret_cast<const s16x8*>(&lB[cur][o * 32 + (lane >> 4) * 8]);
      acc[nt] = mfma16(af, bfr, acc[nt]);
    }
    if (kk < 23) { writeB(cur ^ 1); if (kk < 22) loadB(kk + 2); }
    __syncthreads();
  }

  #pragma unroll
  for (int nt = 0; nt < 8; ++nt)
    #pragma unroll
    for (int r = 0; r < 4; ++r) {
      size_t row = row0 + wm * 16 + (lane >> 4) * 4 + r;
      int col = wn * 128 + nt * 16 + (lane & 15);
      outp[row * 256 + col] = acc[nt][r];
    }
}

// ---------------------------------------------------------------------------
extern "C" void kernel_launch(void* const* d_in, const int* in_sizes, int n_in,
                              void* d_out, int out_size, void* d_ws, size_t ws_size,
                              hipStream_t stream) {
  (void)in_sizes; (void)n_in; (void)out_size;
  const float* in       = (const float*)d_in[0];
  const float* nu_log   = (const float*)d_in[1];
  const float* theta_log= (const float*)d_in[2];
  const float* gamma_log= (const float*)d_in[3];
  const float* B_re     = (const float*)d_in[4];
  const float* B_im     = (const float*)d_in[5];
  const float* C_re     = (const float*)d_in[6];
  const float* C_im     = (const float*)d_in[7];
  const float* Dm       = (const float*)d_in[8];

  // ws: W1 [0,256K) | W2f [256K,1M) | lam @1M | W2t @1.25M | cl @2M (4M) | cin @6M (4M)
  if (ws_size < (size_t)10 * 1024 * 1024) return;
  char* ws = (char*)d_ws;
  unsigned short* W1 = (unsigned short*)(ws + 0);
  float* W2f   = (float*)(ws + 262144);
  float* lamre  = (float*)(ws + 1048576);
  float* lamim  = lamre + 256;
  float* lamLre = lamre + 512;
  float* lamLim = lamre + 768;
  unsigned short* W2t = (unsigned short*)(ws + 1310720);
  float2* cl  = (float2*)(ws + (size_t)2 * 1024 * 1024);
  float2* cin = (float2*)(ws + (size_t)6 * 1024 * 1024);

  unsigned int* BuP = (unsigned int*)d_out;                  // [0,64MB): Bu -> states -> output
  float* innerRe = (float*)d_out + (size_t)16777216;         // [64,128MB): inner real

  k0_mix<<<1281, 256, 0, stream>>>(nu_log, theta_log, gamma_log, B_re, B_im, C_re, C_im, Dm,
                                   W1, W2f, lamre, lamim, lamLre, lamLim);
  k0b_tile<<<768, 256, 0, stream>>>(W2f, W2t);
  k1_gemm_bu<<<2048, 256, 0, stream>>>(in, W1, BuP);
  k2a_local<<<2048, 256, 0, stream>>>(BuP, lamre, lamim, cl);
  k2b_scan<<<16, 256, 0, stream>>>(cl, cin, lamLre, lamLim);
  k3a_scan<<<2048, 256, 0, stream>>>(BuP, innerRe, cin, lamre, lamim);
  k3b_gemm<<<1024, 512, 0, stream>>>(in, (const unsigned short*)BuP, W2t, (float*)BuP);
}

// Round 11
// 196.646 us; speedup vs baseline: 6.4461x; 1.1605x over previous
//
#include <hip/hip_runtime.h>

// LRU r11: r8-green pipeline, with k2a fused into k1 at REGISTER level
// (Horner over MFMA accumulators + shfl_xor cross-lane sum; no LDS reuse,
// no pointer-type aliasing). k1 lB back to single-buffer (3 blocks/CU).
// d_out = [0,64MB) output f32 | [64,128MB) inner-real f32.
// Region lifecycle:
//   [0,64MB):  k1 writes packed Bu (bf16 re|im u32) -> k3a reads then
//              overwrites per-thread with packed bf16 states -> k3b stages rows
//              (before barriers) then epilogue overwrites with output f32.
//   [64,128MB): untouched until k3a writes inner-real f32 (exact, final).

typedef float  f32x4 __attribute__((ext_vector_type(4)));
typedef short  s16x8 __attribute__((ext_vector_type(8)));

__device__ __forceinline__ unsigned short f2bf(float x) {
  unsigned int u = __builtin_bit_cast(unsigned int, x);
  u += 0x7FFFu + ((u >> 16) & 1u);            // round-to-nearest-even
  return (unsigned short)(u >> 16);
}
__device__ __forceinline__ float bf2f(unsigned int s) {
  unsigned int u = s << 16;
  return __builtin_bit_cast(float, u);
}
__device__ __forceinline__ f32x4 mfma16(s16x8 a, s16x8 b, f32x4 c) {
  return __builtin_amdgcn_mfma_f32_16x16x32_bf16(a, b, c, 0, 0, 0);
}

// ---------------------------------------------------------------------------
// K0: W1 bf16 tiled + W2f f32 [k*256+o] + lam arrays (green, unchanged).
// ---------------------------------------------------------------------------
__global__ void k0_mix(const float* __restrict__ nu_log, const float* __restrict__ theta_log,
                       const float* __restrict__ gamma_log,
                       const float* __restrict__ B_re, const float* __restrict__ B_im,
                       const float* __restrict__ C_re, const float* __restrict__ C_im,
                       const float* __restrict__ Dm,
                       unsigned short* __restrict__ W1, float* __restrict__ W2f,
                       float* __restrict__ lamre, float* __restrict__ lamim,
                       float* __restrict__ lamLre, float* __restrict__ lamLim) {
  int idx = blockIdx.x * 256 + threadIdx.x;
  if (idx < 131072) {
    int ki = idx & 31; int np_ = (idx >> 5) & 511; int kk = idx >> 14;
    int k = kk * 32 + ki; int n = np_ & 255;
    float g = expf(gamma_log[n]);
    float v = (np_ < 256) ? B_re[n * 256 + k] : B_im[n * 256 + k];
    W1[idx] = f2bf(g * v);
  } else if (idx < 327680) {
    int j = idx - 131072;
    int k = j >> 8, o = j & 255;
    float v;
    if (k < 512) { int n = k >> 1; v = (k & 1) ? -C_im[o * 256 + n] : C_re[o * 256 + n]; }
    else         { v = Dm[o * 256 + (k - 512)]; }
    W2f[j] = v;
  } else if (idx < 327936) {
    int n = idx - 327680;
    float la = expf(-expf(nu_log[n]));
    float th = expf(theta_log[n]);
    float lr = la * cosf(th), li = la * sinf(th);
    lamre[n] = lr; lamim[n] = li;
    float r = lr, i = li;
    #pragma unroll
    for (int t = 0; t < 5; ++t) { float nr = r * r - i * i; float ni = 2.f * r * i; r = nr; i = ni; }
    lamLre[n] = r; lamLim[n] = i;
  }
}

// ---------------------------------------------------------------------------
// K0b: tile W2f into bf16 W2t[(kk*256+o)*32+ki] (green, unchanged).
// ---------------------------------------------------------------------------
__global__ void k0b_tile(const float* __restrict__ W2f, unsigned short* __restrict__ W2t) {
  int j = blockIdx.x * 256 + threadIdx.x;          // [0,196608)
  int ki = j & 31, o = (j >> 5) & 255, kk = j >> 13;
  W2t[j] = f2bf(W2f[(kk * 32 + ki) * 256 + o]);
}

// ---------------------------------------------------------------------------
// K1+reduction: Bu = input @ W1^T (bf16 MFMA, r7/r8-green structure, single-
// buffered lB). Packed u32 stores (r8-green). NEW: in-register chunk
// reduction cl[C,n] = sum_j lam^(31-j) Bu_j from the f32 accumulators.
// ---------------------------------------------------------------------------
__global__ __launch_bounds__(256, 3) void k1_red(const float* __restrict__ in,
                                                 const unsigned short* __restrict__ W1,
                                                 unsigned int* __restrict__ BuP,
                                                 const float* __restrict__ lamre,
                                                 const float* __restrict__ lamim,
                                                 float2* __restrict__ cl) {
  __shared__ unsigned short lA[64 * 264];   // 33792 B
  __shared__ unsigned short lB[256 * 40];   // 20480 B
  int tid = threadIdx.x;
  int bid = blockIdx.x;
  int nblk = bid & 1, mblk = bid >> 1;
  int M0 = mblk * 64, n0 = nblk * 128;
  int lane = tid & 63, wid = tid >> 6;
  int wm = wid >> 1, wn = wid & 1;

  // stage A: 64 rows x 256 f32 -> bf16 LDS (r7-green)
  #pragma unroll
  for (int pass = 0; pass < 16; ++pass) {
    int m = pass * 4 + (tid >> 6);
    int h0 = (tid & 63) * 4;
    float4 v = *reinterpret_cast<const float4*>(in + (size_t)(M0 + m) * 256 + h0);
    ushort4 s; s.x = f2bf(v.x); s.y = f2bf(v.y); s.z = f2bf(v.z); s.w = f2bf(v.w);
    *reinterpret_cast<ushort4*>(&lA[m * 264 + h0]) = s;
  }

  f32x4 acc[2][4][2];
  #pragma unroll
  for (int a = 0; a < 2; ++a)
    #pragma unroll
    for (int b = 0; b < 4; ++b)
      #pragma unroll
      for (int p = 0; p < 2; ++p) acc[a][b][p] = f32x4{0.f, 0.f, 0.f, 0.f};

  for (int kk = 0; kk < 8; ++kk) {
    __syncthreads();
    // stage B tile (r7-green): 128 re rows + 128 im rows, 32 bf16 each
    {
      const unsigned short* src_re = W1 + ((size_t)kk * 512 + n0) * 32;
      const unsigned short* src_im = W1 + ((size_t)kk * 512 + 256 + n0) * 32;
      #pragma unroll
      for (int half = 0; half < 2; ++half) {
        const unsigned short* src = half ? src_im : src_re;
        int rbase = half * 128;
        #pragma unroll
        for (int q = 0; q < 2; ++q) {
          int chunk = q * 256 + tid;
          int r = chunk >> 2, off = (chunk & 3) * 8;
          *reinterpret_cast<uint4*>(&lB[(rbase + r) * 40 + off]) =
              *reinterpret_cast<const uint4*>(src + r * 32 + off);
        }
      }
    }
    __syncthreads();
    s16x8 af[2];
    #pragma unroll
    for (int mt = 0; mt < 2; ++mt)
      af[mt] = *reinterpret_cast<const s16x8*>(
          &lA[(wm * 32 + mt * 16 + (lane & 15)) * 264 + kk * 32 + (lane >> 4) * 8]);
    #pragma unroll
    for (int nt = 0; nt < 4; ++nt) {
      #pragma unroll
      for (int p = 0; p < 2; ++p) {
        int r = p * 128 + wn * 64 + nt * 16 + (lane & 15);
        s16x8 bfr = *reinterpret_cast<const s16x8*>(&lB[r * 40 + (lane >> 4) * 8]);
        #pragma unroll
        for (int mt = 0; mt < 2; ++mt)
          acc[mt][nt][p] = mfma16(af[mt], bfr, acc[mt][nt][p]);
      }
    }
  }

  // epilogue: pack (re,im) bf16 pairs (r8-green)
  #pragma unroll
  for (int mt = 0; mt < 2; ++mt)
    #pragma unroll
    for (int nt = 0; nt < 4; ++nt)
      #pragma unroll
      for (int r = 0; r < 4; ++r) {
        int m = M0 + wm * 32 + mt * 16 + (lane >> 4) * 4 + r;
        int n = n0 + wn * 64 + nt * 16 + (lane & 15);
        unsigned int pk = (unsigned int)f2bf(acc[mt][nt][0][r]) |
                          ((unsigned int)f2bf(acc[mt][nt][1][r]) << 16);
        BuP[(size_t)m * 256 + n] = pk;
      }

  // NEW: in-register chunk reduction. Thread rows: t = mt*16 + q*4 + r in
  // chunk (wm) of this block; X = sum_t lam^{31-t} Bu_t.
  // 31-t = (3-r) + (28 - 16*mt - 4*q)  ->  X = lam^{28-4q} H_0 + lam^{12-4q} H_1,
  // H_mt = Horner_r(lam; acc[mt]). Sum over q via shfl_xor(16,32); q==0 writes.
  {
    int q = lane >> 4;
    #pragma unroll
    for (int nt = 0; nt < 4; ++nt) {
      int n = n0 + wn * 64 + nt * 16 + (lane & 15);
      float lr = lamre[n], li = lamim[n];
      // Horner over r for each mt (complex): H = ((b0*l + b1)*l + b2)*l + b3
      float hr[2], hi[2];
      #pragma unroll
      for (int mt = 0; mt < 2; ++mt) {
        float xr = 0.f, xi = 0.f;
        #pragma unroll
        for (int r = 0; r < 4; ++r) {
          float br = acc[mt][nt][0][r], bi = acc[mt][nt][1][r];
          float nr2 = lr * xr - li * xi + br;
          float ni2 = lr * xi + li * xr + bi;
          xr = nr2; xi = ni2;
        }
        hr[mt] = xr; hi[mt] = xi;
      }
      // powers: l4 = lam^4, p8, p12, p16
      float l2r = lr * lr - li * li, l2i = 2.f * lr * li;
      float l4r = l2r * l2r - l2i * l2i, l4i = 2.f * l2r * l2i;
      float p8r = l4r * l4r - l4i * l4i, p8i = 2.f * l4r * l4i;
      float p12r = p8r * l4r - p8i * l4i, p12i = p8r * l4i + p8i * l4r;
      float p16r = p8r * p8r - p8i * p8i, p16i = 2.f * p8r * p8i;
      float e1r, e1i;                    // lam^{12-4q}
      if (q == 0)      { e1r = p12r; e1i = p12i; }
      else if (q == 1) { e1r = p8r;  e1i = p8i;  }
      else if (q == 2) { e1r = l4r;  e1i = l4i;  }
      else             { e1r = 1.f;  e1i = 0.f;  }
      float e0r = e1r * p16r - e1i * p16i;  // lam^{28-4q}
      float e0i = e1r * p16i + e1i * p16r;
      float Tr = e0r * hr[0] - e0i * hi[0] + e1r * hr[1] - e1i * hi[1];
      float Ti = e0r * hi[0] + e0i * hr[0] + e1r * hi[1] + e1i * hr[1];
      Tr += __shfl_xor(Tr, 16); Ti += __shfl_xor(Ti, 16);
      Tr += __shfl_xor(Tr, 32); Ti += __shfl_xor(Ti, 32);
      if (q == 0) {
        size_t C = (size_t)mblk * 2 + wm;
        cl[C * 256 + n] = make_float2(Tr, Ti);
      }
    }
  }
}

// ---------------------------------------------------------------------------
// K2b: carry scan over 128 chunk carries per (b,n) (green, unchanged).
// ---------------------------------------------------------------------------
__global__ void k2b_scan(const float2* __restrict__ cl, float2* __restrict__ cin,
                         const float* __restrict__ lamLre, const float* __restrict__ lamLim) {
  int b = blockIdx.x, n = threadIdx.x;
  float lr = lamLre[n], li = lamLim[n];
  float sr = 0.f, si = 0.f;
  #pragma unroll 4
  for (int c = 0; c < 128; ++c) {
    size_t idx = ((size_t)b * 128 + c) * 256 + n;
    float2 L = cl[idx];
    cin[idx] = make_float2(sr, si);
    float nr = lr * sr - li * si + L.x;
    float ni = lr * si + li * sr + L.y;
    sr = nr; si = ni;
  }
}

// ---------------------------------------------------------------------------
// K3a: f32 scan (green, unchanged). Reads packed Bu, overwrites with packed
// bf16 states (same thread/idx), writes inner-real f32 to second region.
// ---------------------------------------------------------------------------
__global__ __launch_bounds__(256) void k3a_scan(unsigned int* BuP, float* __restrict__ innerRe,
                                                const float2* __restrict__ cin,
                                                const float* __restrict__ lamre,
                                                const float* __restrict__ lamim) {
  int b = blockIdx.x >> 7, c = blockIdx.x & 127, n = threadIdx.x;
  size_t row0 = (size_t)b * 4096 + c * 32;
  float2 s0 = cin[((size_t)b * 128 + c) * 256 + n];
  float sr = s0.x, si = s0.y;
  float lr = lamre[n], li = lamim[n];
  #pragma unroll 4
  for (int j = 0; j < 32; ++j) {
    size_t idx = (row0 + j) * 256 + n;
    unsigned int v = BuP[idx];                          // read Bu FIRST
    BuP[idx] = (unsigned int)f2bf(sr) | ((unsigned int)f2bf(si) << 16);
    innerRe[idx] = sr;                                  // inner real (pre-state)
    float br = bf2f(v & 0xffffu), bi = bf2f(v >> 16);
    float nr = lr * sr - li * si + br;
    float ni = lr * si + li * sr + bi;
    sr = nr; si = ni;
  }
}

// ---------------------------------------------------------------------------
// K3b: r8's EXACT green version. M=64/block, 512 threads (4M x 2N waves).
// Double-buffered lB (stride 32), register-prefetch, one barrier per K-step.
// Epilogue overwrites this block's SPack rows with the final output.
// ---------------------------------------------------------------------------
__global__ __launch_bounds__(512, 2) void k3b_gemm(const float* __restrict__ in,
                                                   const unsigned short* SPack,
                                                   const unsigned short* __restrict__ W2t,
                                                   float* outp) {
  __shared__ unsigned short lA[64 * 776];         // 99328 B
  __shared__ unsigned short lB[2][256 * 32];      // 2 x 16384 B
  int tid = threadIdx.x, lane = tid & 63, wid = tid >> 6;
  int wm = wid >> 1, wn = wid & 1;                 // 4 M-waves x 2 N-waves
  size_t row0 = (size_t)blockIdx.x * 64;

  // stage A cols 0..511: packed bf16 states (64 rows x 512 shorts)
  #pragma unroll
  for (int i = 0; i < 8; ++i) {
    int chunk = i * 512 + tid;                     // [0,4096) chunks of 8 shorts
    int r = chunk >> 6, c8 = (chunk & 63) * 8;
    *reinterpret_cast<uint4*>(&lA[r * 776 + c8]) =
        *reinterpret_cast<const uint4*>(SPack + (row0 + r) * 512 + c8);
  }
  // stage A cols 512..767: u f32 -> bf16
  #pragma unroll
  for (int pass = 0; pass < 8; ++pass) {
    int m = pass * 8 + (tid >> 6);
    int h0 = (tid & 63) * 4;
    float4 v = *reinterpret_cast<const float4*>(in + (row0 + m) * 256 + h0);
    ushort4 s; s.x = f2bf(v.x); s.y = f2bf(v.y); s.z = f2bf(v.z); s.w = f2bf(v.w);
    *reinterpret_cast<ushort4*>(&lA[m * 776 + 512 + h0]) = s;
  }

  uint4 pre[2];
  auto loadB = [&](int kk) {
    #pragma unroll
    for (int q = 0; q < 2; ++q)
      pre[q] = *reinterpret_cast<const uint4*>(W2t + (size_t)kk * 8192 + (q * 512 + tid) * 8);
  };
  auto writeB = [&](int buf) {
    #pragma unroll
    for (int q = 0; q < 2; ++q)
      *reinterpret_cast<uint4*>(&lB[buf][(q * 512 + tid) * 8]) = pre[q];
  };

  loadB(0); writeB(0); loadB(1);
  __syncthreads();

  f32x4 acc[8];
  #pragma unroll
  for (int nt = 0; nt < 8; ++nt) acc[nt] = f32x4{0.f, 0.f, 0.f, 0.f};

  for (int kk = 0; kk < 24; ++kk) {
    int cur = kk & 1;
    s16x8 af = *reinterpret_cast<const s16x8*>(
        &lA[(wm * 16 + (lane & 15)) * 776 + kk * 32 + (lane >> 4) * 8]);
    #pragma unroll
    for (int nt = 0; nt < 8; ++nt) {
      int o = wn * 128 + nt * 16 + (lane & 15);
      s16x8 bfr = *reinterpret_cast<const s16x8*>(&lB[cur][o * 32 + (lane >> 4) * 8]);
      acc[nt] = mfma16(af, bfr, acc[nt]);
    }
    if (kk < 23) { writeB(cur ^ 1); if (kk < 22) loadB(kk + 2); }
    __syncthreads();
  }

  #pragma unroll
  for (int nt = 0; nt < 8; ++nt)
    #pragma unroll
    for (int r = 0; r < 4; ++r) {
      size_t row = row0 + wm * 16 + (lane >> 4) * 4 + r;
      int col = wn * 128 + nt * 16 + (lane & 15);
      outp[row * 256 + col] = acc[nt][r];
    }
}

// ---------------------------------------------------------------------------
extern "C" void kernel_launch(void* const* d_in, const int* in_sizes, int n_in,
                              void* d_out, int out_size, void* d_ws, size_t ws_size,
                              hipStream_t stream) {
  (void)in_sizes; (void)n_in; (void)out_size;
  const float* in       = (const float*)d_in[0];
  const float* nu_log   = (const float*)d_in[1];
  const float* theta_log= (const float*)d_in[2];
  const float* gamma_log= (const float*)d_in[3];
  const float* B_re     = (const float*)d_in[4];
  const float* B_im     = (const float*)d_in[5];
  const float* C_re     = (const float*)d_in[6];
  const float* C_im     = (const float*)d_in[7];
  const float* Dm       = (const float*)d_in[8];

  // ws: W1 [0,256K) | W2f [256K,1M) | lam @1M | W2t @1.25M | cl @2M (4M) | cin @6M (4M)
  if (ws_size < (size_t)10 * 1024 * 1024) return;
  char* ws = (char*)d_ws;
  unsigned short* W1 = (unsigned short*)(ws + 0);
  float* W2f   = (float*)(ws + 262144);
  float* lamre  = (float*)(ws + 1048576);
  float* lamim  = lamre + 256;
  float* lamLre = lamre + 512;
  float* lamLim = lamre + 768;
  unsigned short* W2t = (unsigned short*)(ws + 1310720);
  float2* cl  = (float2*)(ws + (size_t)2 * 1024 * 1024);
  float2* cin = (float2*)(ws + (size_t)6 * 1024 * 1024);

  unsigned int* BuP = (unsigned int*)d_out;                  // [0,64MB): Bu -> states -> output
  float* innerRe = (float*)d_out + (size_t)16777216;         // [64,128MB): inner real

  k0_mix<<<1281, 256, 0, stream>>>(nu_log, theta_log, gamma_log, B_re, B_im, C_re, C_im, Dm,
                                   W1, W2f, lamre, lamim, lamLre, lamLim);
  k0b_tile<<<768, 256, 0, stream>>>(W2f, W2t);
  k1_red<<<2048, 256, 0, stream>>>(in, W1, BuP, lamre, lamim, cl);
  k2b_scan<<<16, 256, 0, stream>>>(cl, cin, lamLre, lamLim);
  k3a_scan<<<2048, 256, 0, stream>>>(BuP, innerRe, cin, lamre, lamim);
  k3b_gemm<<<1024, 512, 0, stream>>>(in, (const unsigned short*)BuP, W2t, (float*)BuP);
}

// Round 12
// 174.581 us; speedup vs baseline: 7.2608x; 1.1264x over previous
//
#include <hip/hip_runtime.h>

// LRU r12: k3b redesigned as B-register-stationary GEMM (LDS-read-bound fix).
// Everything else byte-identical to r11-green.
// d_out = [0,64MB) output f32 | [64,128MB) inner-real f32.
// Region lifecycle:
//   [0,64MB):  k1 writes packed Bu (bf16 re|im u32) -> k3a reads then
//              overwrites per-thread with packed bf16 states -> k3b stages its
//              32 rows (before barrier) then epilogue overwrites with output.
//   [64,128MB): untouched until k3a writes inner-real f32 (exact, final).

typedef float  f32x4 __attribute__((ext_vector_type(4)));
typedef short  s16x8 __attribute__((ext_vector_type(8)));

__device__ __forceinline__ unsigned short f2bf(float x) {
  unsigned int u = __builtin_bit_cast(unsigned int, x);
  u += 0x7FFFu + ((u >> 16) & 1u);            // round-to-nearest-even
  return (unsigned short)(u >> 16);
}
__device__ __forceinline__ float bf2f(unsigned int s) {
  unsigned int u = s << 16;
  return __builtin_bit_cast(float, u);
}
__device__ __forceinline__ f32x4 mfma16(s16x8 a, s16x8 b, f32x4 c) {
  return __builtin_amdgcn_mfma_f32_16x16x32_bf16(a, b, c, 0, 0, 0);
}

// ---------------------------------------------------------------------------
// K0: W1 bf16 tiled + W2f f32 [k*256+o] + lam arrays (green, unchanged).
// ---------------------------------------------------------------------------
__global__ void k0_mix(const float* __restrict__ nu_log, const float* __restrict__ theta_log,
                       const float* __restrict__ gamma_log,
                       const float* __restrict__ B_re, const float* __restrict__ B_im,
                       const float* __restrict__ C_re, const float* __restrict__ C_im,
                       const float* __restrict__ Dm,
                       unsigned short* __restrict__ W1, float* __restrict__ W2f,
                       float* __restrict__ lamre, float* __restrict__ lamim,
                       float* __restrict__ lamLre, float* __restrict__ lamLim) {
  int idx = blockIdx.x * 256 + threadIdx.x;
  if (idx < 131072) {
    int ki = idx & 31; int np_ = (idx >> 5) & 511; int kk = idx >> 14;
    int k = kk * 32 + ki; int n = np_ & 255;
    float g = expf(gamma_log[n]);
    float v = (np_ < 256) ? B_re[n * 256 + k] : B_im[n * 256 + k];
    W1[idx] = f2bf(g * v);
  } else if (idx < 327680) {
    int j = idx - 131072;
    int k = j >> 8, o = j & 255;
    float v;
    if (k < 512) { int n = k >> 1; v = (k & 1) ? -C_im[o * 256 + n] : C_re[o * 256 + n]; }
    else         { v = Dm[o * 256 + (k - 512)]; }
    W2f[j] = v;
  } else if (idx < 327936) {
    int n = idx - 327680;
    float la = expf(-expf(nu_log[n]));
    float th = expf(theta_log[n]);
    float lr = la * cosf(th), li = la * sinf(th);
    lamre[n] = lr; lamim[n] = li;
    float r = lr, i = li;
    #pragma unroll
    for (int t = 0; t < 5; ++t) { float nr = r * r - i * i; float ni = 2.f * r * i; r = nr; i = ni; }
    lamLre[n] = r; lamLim[n] = i;
  }
}

// ---------------------------------------------------------------------------
// K0b: tile W2f into bf16 W2t[(kk*256+o)*32+ki] (green, unchanged).
// ---------------------------------------------------------------------------
__global__ void k0b_tile(const float* __restrict__ W2f, unsigned short* __restrict__ W2t) {
  int j = blockIdx.x * 256 + threadIdx.x;          // [0,196608)
  int ki = j & 31, o = (j >> 5) & 255, kk = j >> 13;
  W2t[j] = f2bf(W2f[(kk * 32 + ki) * 256 + o]);
}

// ---------------------------------------------------------------------------
// K1+reduction (green r11, unchanged): Bu-GEMM, packed u32 stores, in-register
// chunk reduction via Horner + shfl_xor.
// ---------------------------------------------------------------------------
__global__ __launch_bounds__(256, 3) void k1_red(const float* __restrict__ in,
                                                 const unsigned short* __restrict__ W1,
                                                 unsigned int* __restrict__ BuP,
                                                 const float* __restrict__ lamre,
                                                 const float* __restrict__ lamim,
                                                 float2* __restrict__ cl) {
  __shared__ unsigned short lA[64 * 264];   // 33792 B
  __shared__ unsigned short lB[256 * 40];   // 20480 B
  int tid = threadIdx.x;
  int bid = blockIdx.x;
  int nblk = bid & 1, mblk = bid >> 1;
  int M0 = mblk * 64, n0 = nblk * 128;
  int lane = tid & 63, wid = tid >> 6;
  int wm = wid >> 1, wn = wid & 1;

  #pragma unroll
  for (int pass = 0; pass < 16; ++pass) {
    int m = pass * 4 + (tid >> 6);
    int h0 = (tid & 63) * 4;
    float4 v = *reinterpret_cast<const float4*>(in + (size_t)(M0 + m) * 256 + h0);
    ushort4 s; s.x = f2bf(v.x); s.y = f2bf(v.y); s.z = f2bf(v.z); s.w = f2bf(v.w);
    *reinterpret_cast<ushort4*>(&lA[m * 264 + h0]) = s;
  }

  f32x4 acc[2][4][2];
  #pragma unroll
  for (int a = 0; a < 2; ++a)
    #pragma unroll
    for (int b = 0; b < 4; ++b)
      #pragma unroll
      for (int p = 0; p < 2; ++p) acc[a][b][p] = f32x4{0.f, 0.f, 0.f, 0.f};

  for (int kk = 0; kk < 8; ++kk) {
    __syncthreads();
    {
      const unsigned short* src_re = W1 + ((size_t)kk * 512 + n0) * 32;
      const unsigned short* src_im = W1 + ((size_t)kk * 512 + 256 + n0) * 32;
      #pragma unroll
      for (int half = 0; half < 2; ++half) {
        const unsigned short* src = half ? src_im : src_re;
        int rbase = half * 128;
        #pragma unroll
        for (int q = 0; q < 2; ++q) {
          int chunk = q * 256 + tid;
          int r = chunk >> 2, off = (chunk & 3) * 8;
          *reinterpret_cast<uint4*>(&lB[(rbase + r) * 40 + off]) =
              *reinterpret_cast<const uint4*>(src + r * 32 + off);
        }
      }
    }
    __syncthreads();
    s16x8 af[2];
    #pragma unroll
    for (int mt = 0; mt < 2; ++mt)
      af[mt] = *reinterpret_cast<const s16x8*>(
          &lA[(wm * 32 + mt * 16 + (lane & 15)) * 264 + kk * 32 + (lane >> 4) * 8]);
    #pragma unroll
    for (int nt = 0; nt < 4; ++nt) {
      #pragma unroll
      for (int p = 0; p < 2; ++p) {
        int r = p * 128 + wn * 64 + nt * 16 + (lane & 15);
        s16x8 bfr = *reinterpret_cast<const s16x8*>(&lB[r * 40 + (lane >> 4) * 8]);
        #pragma unroll
        for (int mt = 0; mt < 2; ++mt)
          acc[mt][nt][p] = mfma16(af[mt], bfr, acc[mt][nt][p]);
      }
    }
  }

  #pragma unroll
  for (int mt = 0; mt < 2; ++mt)
    #pragma unroll
    for (int nt = 0; nt < 4; ++nt)
      #pragma unroll
      for (int r = 0; r < 4; ++r) {
        int m = M0 + wm * 32 + mt * 16 + (lane >> 4) * 4 + r;
        int n = n0 + wn * 64 + nt * 16 + (lane & 15);
        unsigned int pk = (unsigned int)f2bf(acc[mt][nt][0][r]) |
                          ((unsigned int)f2bf(acc[mt][nt][1][r]) << 16);
        BuP[(size_t)m * 256 + n] = pk;
      }

  {
    int q = lane >> 4;
    #pragma unroll
    for (int nt = 0; nt < 4; ++nt) {
      int n = n0 + wn * 64 + nt * 16 + (lane & 15);
      float lr = lamre[n], li = lamim[n];
      float hr[2], hi[2];
      #pragma unroll
      for (int mt = 0; mt < 2; ++mt) {
        float xr = 0.f, xi = 0.f;
        #pragma unroll
        for (int r = 0; r < 4; ++r) {
          float br = acc[mt][nt][0][r], bi = acc[mt][nt][1][r];
          float nr2 = lr * xr - li * xi + br;
          float ni2 = lr * xi + li * xr + bi;
          xr = nr2; xi = ni2;
        }
        hr[mt] = xr; hi[mt] = xi;
      }
      float l2r = lr * lr - li * li, l2i = 2.f * lr * li;
      float l4r = l2r * l2r - l2i * l2i, l4i = 2.f * l2r * l2i;
      float p8r = l4r * l4r - l4i * l4i, p8i = 2.f * l4r * l4i;
      float p12r = p8r * l4r - p8i * l4i, p12i = p8r * l4i + p8i * l4r;
      float p16r = p8r * p8r - p8i * p8i, p16i = 2.f * p8r * p8i;
      float e1r, e1i;
      if (q == 0)      { e1r = p12r; e1i = p12i; }
      else if (q == 1) { e1r = p8r;  e1i = p8i;  }
      else if (q == 2) { e1r = l4r;  e1i = l4i;  }
      else             { e1r = 1.f;  e1i = 0.f;  }
      float e0r = e1r * p16r - e1i * p16i;
      float e0i = e1r * p16i + e1i * p16r;
      float Tr = e0r * hr[0] - e0i * hi[0] + e1r * hr[1] - e1i * hi[1];
      float Ti = e0r * hi[0] + e0i * hr[0] + e1r * hi[1] + e1i * hr[1];
      Tr += __shfl_xor(Tr, 16); Ti += __shfl_xor(Ti, 16);
      Tr += __shfl_xor(Tr, 32); Ti += __shfl_xor(Ti, 32);
      if (q == 0) {
        size_t C = (size_t)mblk * 2 + wm;
        cl[C * 256 + n] = make_float2(Tr, Ti);
      }
    }
  }
}

// ---------------------------------------------------------------------------
// K2b: carry scan (green, unchanged).
// ---------------------------------------------------------------------------
__global__ void k2b_scan(const float2* __restrict__ cl, float2* __restrict__ cin,
                         const float* __restrict__ lamLre, const float* __restrict__ lamLim) {
  int b = blockIdx.x, n = threadIdx.x;
  float lr = lamLre[n], li = lamLim[n];
  float sr = 0.f, si = 0.f;
  #pragma unroll 4
  for (int c = 0; c < 128; ++c) {
    size_t idx = ((size_t)b * 128 + c) * 256 + n;
    float2 L = cl[idx];
    cin[idx] = make_float2(sr, si);
    float nr = lr * sr - li * si + L.x;
    float ni = lr * si + li * sr + L.y;
    sr = nr; si = ni;
  }
}

// ---------------------------------------------------------------------------
// K3a: f32 scan (green, unchanged).
// ---------------------------------------------------------------------------
__global__ __launch_bounds__(256) void k3a_scan(unsigned int* BuP, float* __restrict__ innerRe,
                                                const float2* __restrict__ cin,
                                                const float* __restrict__ lamre,
                                                const float* __restrict__ lamim) {
  int b = blockIdx.x >> 7, c = blockIdx.x & 127, n = threadIdx.x;
  size_t row0 = (size_t)b * 4096 + c * 32;
  float2 s0 = cin[((size_t)b * 128 + c) * 256 + n];
  float sr = s0.x, si = s0.y;
  float lr = lamre[n], li = lamim[n];
  #pragma unroll 4
  for (int j = 0; j < 32; ++j) {
    size_t idx = (row0 + j) * 256 + n;
    unsigned int v = BuP[idx];                          // read Bu FIRST
    BuP[idx] = (unsigned int)f2bf(sr) | ((unsigned int)f2bf(si) << 16);
    innerRe[idx] = sr;                                  // inner real (pre-state)
    float br = bf2f(v & 0xffffu), bi = bf2f(v >> 16);
    float nr = lr * sr - li * si + br;
    float ni = lr * si + li * sr + bi;
    sr = nr; si = ni;
  }
}

// ---------------------------------------------------------------------------
// K3b NEW: B-register-stationary output GEMM.
// Grid 2048, M=32/block, 512 thr = 8 waves; wave wn owns cols wn*32..+31
// (2 col-tiles of 16). B-frags held in regs, loaded from W2t (L2) in 2
// K-phases of 12 steps (in-place reload, 96 VGPR). Per kk: 2 lA reads +
// 4 MFMA. One barrier total. Epilogue overwrites own SPack rows with output.
// ---------------------------------------------------------------------------
__global__ __launch_bounds__(512, 1) void k3b_breg(const float* __restrict__ in,
                                                   const unsigned short* SPack,
                                                   const unsigned short* __restrict__ W2t,
                                                   float* outp) {
  __shared__ unsigned short lA[32 * 776];   // 49664 B
  int tid = threadIdx.x, lane = tid & 63, wn = tid >> 6;
  int l15 = lane & 15, q = lane >> 4;
  size_t row0 = (size_t)blockIdx.x * 32;

  s16x8 breg[2][12];
  auto loadB = [&](int p) {
    #pragma unroll
    for (int ct = 0; ct < 2; ++ct)
      #pragma unroll
      for (int t = 0; t < 12; ++t) {
        int kk = p * 12 + t;
        int c = wn * 32 + ct * 16 + l15;
        breg[ct][t] = *reinterpret_cast<const s16x8*>(
            W2t + ((size_t)kk * 256 + c) * 32 + q * 8);
      }
  };

  loadB(0);   // overlap with lA staging

  // stage lA cols 0..511: packed bf16 states (32 rows x 512 shorts)
  #pragma unroll
  for (int i = 0; i < 4; ++i) {
    int chunk = i * 512 + tid;              // 2048 chunks of 8 shorts
    int r = chunk >> 6, c8 = (chunk & 63) * 8;
    *reinterpret_cast<uint4*>(&lA[r * 776 + c8]) =
        *reinterpret_cast<const uint4*>(SPack + (row0 + r) * 512 + c8);
  }
  // stage lA cols 512..767: u f32 -> bf16
  #pragma unroll
  for (int i = 0; i < 4; ++i) {
    int chunk = i * 512 + tid;              // 2048 float4 chunks
    int m = chunk >> 6, h0 = (chunk & 63) * 4;
    float4 v = *reinterpret_cast<const float4*>(in + (row0 + m) * 256 + h0);
    ushort4 s; s.x = f2bf(v.x); s.y = f2bf(v.y); s.z = f2bf(v.z); s.w = f2bf(v.w);
    *reinterpret_cast<ushort4*>(&lA[m * 776 + 512 + h0]) = s;
  }
  __syncthreads();

  f32x4 acc[2][2];
  #pragma unroll
  for (int mt = 0; mt < 2; ++mt)
    #pragma unroll
    for (int ct = 0; ct < 2; ++ct) acc[mt][ct] = f32x4{0.f, 0.f, 0.f, 0.f};

  #pragma unroll
  for (int p = 0; p < 2; ++p) {
    if (p) loadB(1);                        // in-place reload (dep-serialized)
    #pragma unroll
    for (int t = 0; t < 12; ++t) {
      int kk = p * 12 + t;
      s16x8 af0 = *reinterpret_cast<const s16x8*>(&lA[(l15) * 776 + kk * 32 + q * 8]);
      s16x8 af1 = *reinterpret_cast<const s16x8*>(&lA[(16 + l15) * 776 + kk * 32 + q * 8]);
      acc[0][0] = mfma16(af0, breg[0][t], acc[0][0]);
      acc[0][1] = mfma16(af0, breg[1][t], acc[0][1]);
      acc[1][0] = mfma16(af1, breg[0][t], acc[1][0]);
      acc[1][1] = mfma16(af1, breg[1][t], acc[1][1]);
    }
  }

  // epilogue: overwrite this block's own SPack rows with the final output
  #pragma unroll
  for (int mt = 0; mt < 2; ++mt)
    #pragma unroll
    for (int ct = 0; ct < 2; ++ct)
      #pragma unroll
      for (int r = 0; r < 4; ++r) {
        size_t row = row0 + mt * 16 + q * 4 + r;
        int col = wn * 32 + ct * 16 + l15;
        outp[row * 256 + col] = acc[mt][ct][r];
      }
}

// ---------------------------------------------------------------------------
extern "C" void kernel_launch(void* const* d_in, const int* in_sizes, int n_in,
                              void* d_out, int out_size, void* d_ws, size_t ws_size,
                              hipStream_t stream) {
  (void)in_sizes; (void)n_in; (void)out_size;
  const float* in       = (const float*)d_in[0];
  const float* nu_log   = (const float*)d_in[1];
  const float* theta_log= (const float*)d_in[2];
  const float* gamma_log= (const float*)d_in[3];
  const float* B_re     = (const float*)d_in[4];
  const float* B_im     = (const float*)d_in[5];
  const float* C_re     = (const float*)d_in[6];
  const float* C_im     = (const float*)d_in[7];
  const float* Dm       = (const float*)d_in[8];

  // ws: W1 [0,256K) | W2f [256K,1M) | lam @1M | W2t @1.25M | cl @2M (4M) | cin @6M (4M)
  if (ws_size < (size_t)10 * 1024 * 1024) return;
  char* ws = (char*)d_ws;
  unsigned short* W1 = (unsigned short*)(ws + 0);
  float* W2f   = (float*)(ws + 262144);
  float* lamre  = (float*)(ws + 1048576);
  float* lamim  = lamre + 256;
  float* lamLre = lamre + 512;
  float* lamLim = lamre + 768;
  unsigned short* W2t = (unsigned short*)(ws + 1310720);
  float2* cl  = (float2*)(ws + (size_t)2 * 1024 * 1024);
  float2* cin = (float2*)(ws + (size_t)6 * 1024 * 1024);

  unsigned int* BuP = (unsigned int*)d_out;                  // [0,64MB): Bu -> states -> output
  float* innerRe = (float*)d_out + (size_t)16777216;         // [64,128MB): inner real

  k0_mix<<<1281, 256, 0, stream>>>(nu_log, theta_log, gamma_log, B_re, B_im, C_re, C_im, Dm,
                                   W1, W2f, lamre, lamim, lamLre, lamLim);
  k0b_tile<<<768, 256, 0, stream>>>(W2f, W2t);
  k1_red<<<2048, 256, 0, stream>>>(in, W1, BuP, lamre, lamim, cl);
  k2b_scan<<<16, 256, 0, stream>>>(cl, cin, lamLre, lamLim);
  k3a_scan<<<2048, 256, 0, stream>>>(BuP, innerRe, cin, lamre, lamim);
  k3b_breg<<<2048, 512, 0, stream>>>(in, (const unsigned short*)BuP, W2t, (float*)BuP);
}

// Round 13
// 168.621 us; speedup vs baseline: 7.5174x; 1.0354x over previous
//
#include <hip/hip_runtime.h>

// LRU r13: k3b_breg v2 — 2 blocks/CU (launch_bounds(512,4)) + double-buffered
// B-register phases (6 x 4 kk-steps). Everything else byte-identical to r12.
// d_out = [0,64MB) output f32 | [64,128MB) inner-real f32.
// Region lifecycle:
//   [0,64MB):  k1 writes packed Bu (bf16 re|im u32) -> k3a reads then
//              overwrites per-thread with packed bf16 states -> k3b stages its
//              32 rows (before barrier) then epilogue overwrites with output.
//   [64,128MB): untouched until k3a writes inner-real f32 (exact, final).

typedef float  f32x4 __attribute__((ext_vector_type(4)));
typedef short  s16x8 __attribute__((ext_vector_type(8)));

__device__ __forceinline__ unsigned short f2bf(float x) {
  unsigned int u = __builtin_bit_cast(unsigned int, x);
  u += 0x7FFFu + ((u >> 16) & 1u);            // round-to-nearest-even
  return (unsigned short)(u >> 16);
}
__device__ __forceinline__ float bf2f(unsigned int s) {
  unsigned int u = s << 16;
  return __builtin_bit_cast(float, u);
}
__device__ __forceinline__ f32x4 mfma16(s16x8 a, s16x8 b, f32x4 c) {
  return __builtin_amdgcn_mfma_f32_16x16x32_bf16(a, b, c, 0, 0, 0);
}

// ---------------------------------------------------------------------------
// K0: W1 bf16 tiled + W2f f32 [k*256+o] + lam arrays (green, unchanged).
// ---------------------------------------------------------------------------
__global__ void k0_mix(const float* __restrict__ nu_log, const float* __restrict__ theta_log,
                       const float* __restrict__ gamma_log,
                       const float* __restrict__ B_re, const float* __restrict__ B_im,
                       const float* __restrict__ C_re, const float* __restrict__ C_im,
                       const float* __restrict__ Dm,
                       unsigned short* __restrict__ W1, float* __restrict__ W2f,
                       float* __restrict__ lamre, float* __restrict__ lamim,
                       float* __restrict__ lamLre, float* __restrict__ lamLim) {
  int idx = blockIdx.x * 256 + threadIdx.x;
  if (idx < 131072) {
    int ki = idx & 31; int np_ = (idx >> 5) & 511; int kk = idx >> 14;
    int k = kk * 32 + ki; int n = np_ & 255;
    float g = expf(gamma_log[n]);
    float v = (np_ < 256) ? B_re[n * 256 + k] : B_im[n * 256 + k];
    W1[idx] = f2bf(g * v);
  } else if (idx < 327680) {
    int j = idx - 131072;
    int k = j >> 8, o = j & 255;
    float v;
    if (k < 512) { int n = k >> 1; v = (k & 1) ? -C_im[o * 256 + n] : C_re[o * 256 + n]; }
    else         { v = Dm[o * 256 + (k - 512)]; }
    W2f[j] = v;
  } else if (idx < 327936) {
    int n = idx - 327680;
    float la = expf(-expf(nu_log[n]));
    float th = expf(theta_log[n]);
    float lr = la * cosf(th), li = la * sinf(th);
    lamre[n] = lr; lamim[n] = li;
    float r = lr, i = li;
    #pragma unroll
    for (int t = 0; t < 5; ++t) { float nr = r * r - i * i; float ni = 2.f * r * i; r = nr; i = ni; }
    lamLre[n] = r; lamLim[n] = i;
  }
}

// ---------------------------------------------------------------------------
// K0b: tile W2f into bf16 W2t[(kk*256+o)*32+ki] (green, unchanged).
// ---------------------------------------------------------------------------
__global__ void k0b_tile(const float* __restrict__ W2f, unsigned short* __restrict__ W2t) {
  int j = blockIdx.x * 256 + threadIdx.x;          // [0,196608)
  int ki = j & 31, o = (j >> 5) & 255, kk = j >> 13;
  W2t[j] = f2bf(W2f[(kk * 32 + ki) * 256 + o]);
}

// ---------------------------------------------------------------------------
// K1+reduction (green r11, unchanged): Bu-GEMM, packed u32 stores, in-register
// chunk reduction via Horner + shfl_xor.
// ---------------------------------------------------------------------------
__global__ __launch_bounds__(256, 3) void k1_red(const float* __restrict__ in,
                                                 const unsigned short* __restrict__ W1,
                                                 unsigned int* __restrict__ BuP,
                                                 const float* __restrict__ lamre,
                                                 const float* __restrict__ lamim,
                                                 float2* __restrict__ cl) {
  __shared__ unsigned short lA[64 * 264];   // 33792 B
  __shared__ unsigned short lB[256 * 40];   // 20480 B
  int tid = threadIdx.x;
  int bid = blockIdx.x;
  int nblk = bid & 1, mblk = bid >> 1;
  int M0 = mblk * 64, n0 = nblk * 128;
  int lane = tid & 63, wid = tid >> 6;
  int wm = wid >> 1, wn = wid & 1;

  #pragma unroll
  for (int pass = 0; pass < 16; ++pass) {
    int m = pass * 4 + (tid >> 6);
    int h0 = (tid & 63) * 4;
    float4 v = *reinterpret_cast<const float4*>(in + (size_t)(M0 + m) * 256 + h0);
    ushort4 s; s.x = f2bf(v.x); s.y = f2bf(v.y); s.z = f2bf(v.z); s.w = f2bf(v.w);
    *reinterpret_cast<ushort4*>(&lA[m * 264 + h0]) = s;
  }

  f32x4 acc[2][4][2];
  #pragma unroll
  for (int a = 0; a < 2; ++a)
    #pragma unroll
    for (int b = 0; b < 4; ++b)
      #pragma unroll
      for (int p = 0; p < 2; ++p) acc[a][b][p] = f32x4{0.f, 0.f, 0.f, 0.f};

  for (int kk = 0; kk < 8; ++kk) {
    __syncthreads();
    {
      const unsigned short* src_re = W1 + ((size_t)kk * 512 + n0) * 32;
      const unsigned short* src_im = W1 + ((size_t)kk * 512 + 256 + n0) * 32;
      #pragma unroll
      for (int half = 0; half < 2; ++half) {
        const unsigned short* src = half ? src_im : src_re;
        int rbase = half * 128;
        #pragma unroll
        for (int q = 0; q < 2; ++q) {
          int chunk = q * 256 + tid;
          int r = chunk >> 2, off = (chunk & 3) * 8;
          *reinterpret_cast<uint4*>(&lB[(rbase + r) * 40 + off]) =
              *reinterpret_cast<const uint4*>(src + r * 32 + off);
        }
      }
    }
    __syncthreads();
    s16x8 af[2];
    #pragma unroll
    for (int mt = 0; mt < 2; ++mt)
      af[mt] = *reinterpret_cast<const s16x8*>(
          &lA[(wm * 32 + mt * 16 + (lane & 15)) * 264 + kk * 32 + (lane >> 4) * 8]);
    #pragma unroll
    for (int nt = 0; nt < 4; ++nt) {
      #pragma unroll
      for (int p = 0; p < 2; ++p) {
        int r = p * 128 + wn * 64 + nt * 16 + (lane & 15);
        s16x8 bfr = *reinterpret_cast<const s16x8*>(&lB[r * 40 + (lane >> 4) * 8]);
        #pragma unroll
        for (int mt = 0; mt < 2; ++mt)
          acc[mt][nt][p] = mfma16(af[mt], bfr, acc[mt][nt][p]);
      }
    }
  }

  #pragma unroll
  for (int mt = 0; mt < 2; ++mt)
    #pragma unroll
    for (int nt = 0; nt < 4; ++nt)
      #pragma unroll
      for (int r = 0; r < 4; ++r) {
        int m = M0 + wm * 32 + mt * 16 + (lane >> 4) * 4 + r;
        int n = n0 + wn * 64 + nt * 16 + (lane & 15);
        unsigned int pk = (unsigned int)f2bf(acc[mt][nt][0][r]) |
                          ((unsigned int)f2bf(acc[mt][nt][1][r]) << 16);
        BuP[(size_t)m * 256 + n] = pk;
      }

  {
    int q = lane >> 4;
    #pragma unroll
    for (int nt = 0; nt < 4; ++nt) {
      int n = n0 + wn * 64 + nt * 16 + (lane & 15);
      float lr = lamre[n], li = lamim[n];
      float hr[2], hi[2];
      #pragma unroll
      for (int mt = 0; mt < 2; ++mt) {
        float xr = 0.f, xi = 0.f;
        #pragma unroll
        for (int r = 0; r < 4; ++r) {
          float br = acc[mt][nt][0][r], bi = acc[mt][nt][1][r];
          float nr2 = lr * xr - li * xi + br;
          float ni2 = lr * xi + li * xr + bi;
          xr = nr2; xi = ni2;
        }
        hr[mt] = xr; hi[mt] = xi;
      }
      float l2r = lr * lr - li * li, l2i = 2.f * lr * li;
      float l4r = l2r * l2r - l2i * l2i, l4i = 2.f * l2r * l2i;
      float p8r = l4r * l4r - l4i * l4i, p8i = 2.f * l4r * l4i;
      float p12r = p8r * l4r - p8i * l4i, p12i = p8r * l4i + p8i * l4r;
      float p16r = p8r * p8r - p8i * p8i, p16i = 2.f * p8r * p8i;
      float e1r, e1i;
      if (q == 0)      { e1r = p12r; e1i = p12i; }
      else if (q == 1) { e1r = p8r;  e1i = p8i;  }
      else if (q == 2) { e1r = l4r;  e1i = l4i;  }
      else             { e1r = 1.f;  e1i = 0.f;  }
      float e0r = e1r * p16r - e1i * p16i;
      float e0i = e1r * p16i + e1i * p16r;
      float Tr = e0r * hr[0] - e0i * hi[0] + e1r * hr[1] - e1i * hi[1];
      float Ti = e0r * hi[0] + e0i * hr[0] + e1r * hi[1] + e1i * hr[1];
      Tr += __shfl_xor(Tr, 16); Ti += __shfl_xor(Ti, 16);
      Tr += __shfl_xor(Tr, 32); Ti += __shfl_xor(Ti, 32);
      if (q == 0) {
        size_t C = (size_t)mblk * 2 + wm;
        cl[C * 256 + n] = make_float2(Tr, Ti);
      }
    }
  }
}

// ---------------------------------------------------------------------------
// K2b: carry scan (green, unchanged).
// ---------------------------------------------------------------------------
__global__ void k2b_scan(const float2* __restrict__ cl, float2* __restrict__ cin,
                         const float* __restrict__ lamLre, const float* __restrict__ lamLim) {
  int b = blockIdx.x, n = threadIdx.x;
  float lr = lamLre[n], li = lamLim[n];
  float sr = 0.f, si = 0.f;
  #pragma unroll 4
  for (int c = 0; c < 128; ++c) {
    size_t idx = ((size_t)b * 128 + c) * 256 + n;
    float2 L = cl[idx];
    cin[idx] = make_float2(sr, si);
    float nr = lr * sr - li * si + L.x;
    float ni = lr * si + li * sr + L.y;
    sr = nr; si = ni;
  }
}

// ---------------------------------------------------------------------------
// K3a: f32 scan (green, unchanged).
// ---------------------------------------------------------------------------
__global__ __launch_bounds__(256) void k3a_scan(unsigned int* BuP, float* __restrict__ innerRe,
                                                const float2* __restrict__ cin,
                                                const float* __restrict__ lamre,
                                                const float* __restrict__ lamim) {
  int b = blockIdx.x >> 7, c = blockIdx.x & 127, n = threadIdx.x;
  size_t row0 = (size_t)b * 4096 + c * 32;
  float2 s0 = cin[((size_t)b * 128 + c) * 256 + n];
  float sr = s0.x, si = s0.y;
  float lr = lamre[n], li = lamim[n];
  #pragma unroll 4
  for (int j = 0; j < 32; ++j) {
    size_t idx = (row0 + j) * 256 + n;
    unsigned int v = BuP[idx];                          // read Bu FIRST
    BuP[idx] = (unsigned int)f2bf(sr) | ((unsigned int)f2bf(si) << 16);
    innerRe[idx] = sr;                                  // inner real (pre-state)
    float br = bf2f(v & 0xffffu), bi = bf2f(v >> 16);
    float nr = lr * sr - li * si + br;
    float ni = lr * si + li * sr + bi;
    sr = nr; si = ni;
  }
}

// ---------------------------------------------------------------------------
// K3b v2: B-register-stationary GEMM, 2 blocks/CU, double-buffered breg.
// Grid 2048, M=32/block, 512 thr = 8 waves; wave wn owns cols wn*32..+31.
// K = 6 phases x 4 kk-steps; next phase's 8 B-frags load (independent regs)
// while current phase's 16 MFMAs run. All breg indices compile-time static.
// Epilogue overwrites this block's own SPack rows with the final output.
// ---------------------------------------------------------------------------
__global__ __launch_bounds__(512, 4) void k3b_breg(const float* __restrict__ in,
                                                   const unsigned short* SPack,
                                                   const unsigned short* __restrict__ W2t,
                                                   float* outp) {
  __shared__ unsigned short lA[32 * 776];   // 49664 B
  int tid = threadIdx.x, lane = tid & 63, wn = tid >> 6;
  int l15 = lane & 15, q = lane >> 4;
  size_t row0 = (size_t)blockIdx.x * 32;

  s16x8 breg[2][2][4];                      // [buf][ct][t] — 64 VGPR
  auto loadB = [&](int buf, int p) {
    #pragma unroll
    for (int ct = 0; ct < 2; ++ct)
      #pragma unroll
      for (int t = 0; t < 4; ++t) {
        int kk = p * 4 + t;
        int c = wn * 32 + ct * 16 + l15;
        breg[buf][ct][t] = *reinterpret_cast<const s16x8*>(
            W2t + ((size_t)kk * 256 + c) * 32 + q * 8);
      }
  };

  loadB(0, 0);                              // issue early, overlaps staging

  // stage lA cols 0..511: packed bf16 states (32 rows x 512 shorts)
  #pragma unroll
  for (int i = 0; i < 4; ++i) {
    int chunk = i * 512 + tid;              // 2048 chunks of 8 shorts
    int r = chunk >> 6, c8 = (chunk & 63) * 8;
    *reinterpret_cast<uint4*>(&lA[r * 776 + c8]) =
        *reinterpret_cast<const uint4*>(SPack + (row0 + r) * 512 + c8);
  }
  // stage lA cols 512..767: u f32 -> bf16
  #pragma unroll
  for (int i = 0; i < 4; ++i) {
    int chunk = i * 512 + tid;              // 2048 float4 chunks
    int m = chunk >> 6, h0 = (chunk & 63) * 4;
    float4 v = *reinterpret_cast<const float4*>(in + (row0 + m) * 256 + h0);
    ushort4 s; s.x = f2bf(v.x); s.y = f2bf(v.y); s.z = f2bf(v.z); s.w = f2bf(v.w);
    *reinterpret_cast<ushort4*>(&lA[m * 776 + 512 + h0]) = s;
  }
  __syncthreads();

  f32x4 acc[2][2];
  #pragma unroll
  for (int mt = 0; mt < 2; ++mt)
    #pragma unroll
    for (int ct = 0; ct < 2; ++ct) acc[mt][ct] = f32x4{0.f, 0.f, 0.f, 0.f};

  #pragma unroll
  for (int p = 0; p < 6; ++p) {
    const int cur = p & 1;
    if (p < 5) loadB(cur ^ 1, p + 1);       // prefetch next phase into other buf
    #pragma unroll
    for (int t = 0; t < 4; ++t) {
      int kk = p * 4 + t;
      s16x8 af0 = *reinterpret_cast<const s16x8*>(&lA[(l15) * 776 + kk * 32 + q * 8]);
      s16x8 af1 = *reinterpret_cast<const s16x8*>(&lA[(16 + l15) * 776 + kk * 32 + q * 8]);
      acc[0][0] = mfma16(af0, breg[cur][0][t], acc[0][0]);
      acc[0][1] = mfma16(af0, breg[cur][1][t], acc[0][1]);
      acc[1][0] = mfma16(af1, breg[cur][0][t], acc[1][0]);
      acc[1][1] = mfma16(af1, breg[cur][1][t], acc[1][1]);
    }
  }

  // epilogue: overwrite this block's own SPack rows with the final output
  #pragma unroll
  for (int mt = 0; mt < 2; ++mt)
    #pragma unroll
    for (int ct = 0; ct < 2; ++ct)
      #pragma unroll
      for (int r = 0; r < 4; ++r) {
        size_t row = row0 + mt * 16 + q * 4 + r;
        int col = wn * 32 + ct * 16 + l15;
        outp[row * 256 + col] = acc[mt][ct][r];
      }
}

// ---------------------------------------------------------------------------
extern "C" void kernel_launch(void* const* d_in, const int* in_sizes, int n_in,
                              void* d_out, int out_size, void* d_ws, size_t ws_size,
                              hipStream_t stream) {
  (void)in_sizes; (void)n_in; (void)out_size;
  const float* in       = (const float*)d_in[0];
  const float* nu_log   = (const float*)d_in[1];
  const float* theta_log= (const float*)d_in[2];
  const float* gamma_log= (const float*)d_in[3];
  const float* B_re     = (const float*)d_in[4];
  const float* B_im     = (const float*)d_in[5];
  const float* C_re     = (const float*)d_in[6];
  const float* C_im     = (const float*)d_in[7];
  const float* Dm       = (const float*)d_in[8];

  // ws: W1 [0,256K) | W2f [256K,1M) | lam @1M | W2t @1.25M | cl @2M (4M) | cin @6M (4M)
  if (ws_size < (size_t)10 * 1024 * 1024) return;
  char* ws = (char*)d_ws;
  unsigned short* W1 = (unsigned short*)(ws + 0);
  float* W2f   = (float*)(ws + 262144);
  float* lamre  = (float*)(ws + 1048576);
  float* lamim  = lamre + 256;
  float* lamLre = lamre + 512;
  float* lamLim = lamre + 768;
  unsigned short* W2t = (unsigned short*)(ws + 1310720);
  float2* cl  = (float2*)(ws + (size_t)2 * 1024 * 1024);
  float2* cin = (float2*)(ws + (size_t)6 * 1024 * 1024);

  unsigned int* BuP = (unsigned int*)d_out;                  // [0,64MB): Bu -> states -> output
  float* innerRe = (float*)d_out + (size_t)16777216;         // [64,128MB): inner real

  k0_mix<<<1281, 256, 0, stream>>>(nu_log, theta_log, gamma_log, B_re, B_im, C_re, C_im, Dm,
                                   W1, W2f, lamre, lamim, lamLre, lamLim);
  k0b_tile<<<768, 256, 0, stream>>>(W2f, W2t);
  k1_red<<<2048, 256, 0, stream>>>(in, W1, BuP, lamre, lamim, cl);
  k2b_scan<<<16, 256, 0, stream>>>(cl, cin, lamLre, lamLim);
  k3a_scan<<<2048, 256, 0, stream>>>(BuP, innerRe, cin, lamre, lamim);
  k3b_breg<<<2048, 512, 0, stream>>>(in, (const unsigned short*)BuP, W2t, (float*)BuP);
}

// Round 16
// 166.052 us; speedup vs baseline: 7.6337x; 1.0155x over previous
//
#include <hip/hip_runtime.h>

// LRU r16: r13-green pipeline; ONLY k3b changed -> M=64/block, 1024 threads,
// 16 waves x 16-col slices, dbuf B-register-stationary (halves W2t L2 traffic).
// The k3a/k3b split is PERMANENT: all intra-kernel state->MFMA feeds failed
// (r3/r4 LDS, r9/r10 LDS-union, r14/r15 global+fence); split is green.
// d_out = [0,64MB) output f32 | [64,128MB) inner-real f32.
// Region lifecycle:
//   [0,64MB):  k1 writes packed Bu (bf16 re|im u32) -> k3a reads then
//              overwrites per-thread with packed bf16 states -> k3b stages its
//              64 rows (before barrier) then epilogue overwrites with output.
//   [64,128MB): untouched until k3a writes inner-real f32 (exact, final).

typedef float  f32x4 __attribute__((ext_vector_type(4)));
typedef short  s16x8 __attribute__((ext_vector_type(8)));

__device__ __forceinline__ unsigned short f2bf(float x) {
  unsigned int u = __builtin_bit_cast(unsigned int, x);
  u += 0x7FFFu + ((u >> 16) & 1u);            // round-to-nearest-even
  return (unsigned short)(u >> 16);
}
__device__ __forceinline__ float bf2f(unsigned int s) {
  unsigned int u = s << 16;
  return __builtin_bit_cast(float, u);
}
__device__ __forceinline__ f32x4 mfma16(s16x8 a, s16x8 b, f32x4 c) {
  return __builtin_amdgcn_mfma_f32_16x16x32_bf16(a, b, c, 0, 0, 0);
}

// ---------------------------------------------------------------------------
// K0: W1 bf16 tiled + W2f f32 [k*256+o] + lam arrays (green, unchanged).
// ---------------------------------------------------------------------------
__global__ void k0_mix(const float* __restrict__ nu_log, const float* __restrict__ theta_log,
                       const float* __restrict__ gamma_log,
                       const float* __restrict__ B_re, const float* __restrict__ B_im,
                       const float* __restrict__ C_re, const float* __restrict__ C_im,
                       const float* __restrict__ Dm,
                       unsigned short* __restrict__ W1, float* __restrict__ W2f,
                       float* __restrict__ lamre, float* __restrict__ lamim,
                       float* __restrict__ lamLre, float* __restrict__ lamLim) {
  int idx = blockIdx.x * 256 + threadIdx.x;
  if (idx < 131072) {
    int ki = idx & 31; int np_ = (idx >> 5) & 511; int kk = idx >> 14;
    int k = kk * 32 + ki; int n = np_ & 255;
    float g = expf(gamma_log[n]);
    float v = (np_ < 256) ? B_re[n * 256 + k] : B_im[n * 256 + k];
    W1[idx] = f2bf(g * v);
  } else if (idx < 327680) {
    int j = idx - 131072;
    int k = j >> 8, o = j & 255;
    float v;
    if (k < 512) { int n = k >> 1; v = (k & 1) ? -C_im[o * 256 + n] : C_re[o * 256 + n]; }
    else         { v = Dm[o * 256 + (k - 512)]; }
    W2f[j] = v;
  } else if (idx < 327936) {
    int n = idx - 327680;
    float la = expf(-expf(nu_log[n]));
    float th = expf(theta_log[n]);
    float lr = la * cosf(th), li = la * sinf(th);
    lamre[n] = lr; lamim[n] = li;
    float r = lr, i = li;
    #pragma unroll
    for (int t = 0; t < 5; ++t) { float nr = r * r - i * i; float ni = 2.f * r * i; r = nr; i = ni; }
    lamLre[n] = r; lamLim[n] = i;
  }
}

// ---------------------------------------------------------------------------
// K0b: tile W2f into bf16 W2t[(kk*256+o)*32+ki] (green, unchanged).
// ---------------------------------------------------------------------------
__global__ void k0b_tile(const float* __restrict__ W2f, unsigned short* __restrict__ W2t) {
  int j = blockIdx.x * 256 + threadIdx.x;          // [0,196608)
  int ki = j & 31, o = (j >> 5) & 255, kk = j >> 13;
  W2t[j] = f2bf(W2f[(kk * 32 + ki) * 256 + o]);
}

// ---------------------------------------------------------------------------
// K1+reduction (green r11, unchanged): Bu-GEMM, packed u32 stores, in-register
// chunk reduction via Horner + shfl_xor.
// ---------------------------------------------------------------------------
__global__ __launch_bounds__(256, 3) void k1_red(const float* __restrict__ in,
                                                 const unsigned short* __restrict__ W1,
                                                 unsigned int* __restrict__ BuP,
                                                 const float* __restrict__ lamre,
                                                 const float* __restrict__ lamim,
                                                 float2* __restrict__ cl) {
  __shared__ unsigned short lA[64 * 264];   // 33792 B
  __shared__ unsigned short lB[256 * 40];   // 20480 B
  int tid = threadIdx.x;
  int bid = blockIdx.x;
  int nblk = bid & 1, mblk = bid >> 1;
  int M0 = mblk * 64, n0 = nblk * 128;
  int lane = tid & 63, wid = tid >> 6;
  int wm = wid >> 1, wn = wid & 1;

  #pragma unroll
  for (int pass = 0; pass < 16; ++pass) {
    int m = pass * 4 + (tid >> 6);
    int h0 = (tid & 63) * 4;
    float4 v = *reinterpret_cast<const float4*>(in + (size_t)(M0 + m) * 256 + h0);
    ushort4 s; s.x = f2bf(v.x); s.y = f2bf(v.y); s.z = f2bf(v.z); s.w = f2bf(v.w);
    *reinterpret_cast<ushort4*>(&lA[m * 264 + h0]) = s;
  }

  f32x4 acc[2][4][2];
  #pragma unroll
  for (int a = 0; a < 2; ++a)
    #pragma unroll
    for (int b = 0; b < 4; ++b)
      #pragma unroll
      for (int p = 0; p < 2; ++p) acc[a][b][p] = f32x4{0.f, 0.f, 0.f, 0.f};

  for (int kk = 0; kk < 8; ++kk) {
    __syncthreads();
    {
      const unsigned short* src_re = W1 + ((size_t)kk * 512 + n0) * 32;
      const unsigned short* src_im = W1 + ((size_t)kk * 512 + 256 + n0) * 32;
      #pragma unroll
      for (int half = 0; half < 2; ++half) {
        const unsigned short* src = half ? src_im : src_re;
        int rbase = half * 128;
        #pragma unroll
        for (int q = 0; q < 2; ++q) {
          int chunk = q * 256 + tid;
          int r = chunk >> 2, off = (chunk & 3) * 8;
          *reinterpret_cast<uint4*>(&lB[(rbase + r) * 40 + off]) =
              *reinterpret_cast<const uint4*>(src + r * 32 + off);
        }
      }
    }
    __syncthreads();
    s16x8 af[2];
    #pragma unroll
    for (int mt = 0; mt < 2; ++mt)
      af[mt] = *reinterpret_cast<const s16x8*>(
          &lA[(wm * 32 + mt * 16 + (lane & 15)) * 264 + kk * 32 + (lane >> 4) * 8]);
    #pragma unroll
    for (int nt = 0; nt < 4; ++nt) {
      #pragma unroll
      for (int p = 0; p < 2; ++p) {
        int r = p * 128 + wn * 64 + nt * 16 + (lane & 15);
        s16x8 bfr = *reinterpret_cast<const s16x8*>(&lB[r * 40 + (lane >> 4) * 8]);
        #pragma unroll
        for (int mt = 0; mt < 2; ++mt)
          acc[mt][nt][p] = mfma16(af[mt], bfr, acc[mt][nt][p]);
      }
    }
  }

  #pragma unroll
  for (int mt = 0; mt < 2; ++mt)
    #pragma unroll
    for (int nt = 0; nt < 4; ++nt)
      #pragma unroll
      for (int r = 0; r < 4; ++r) {
        int m = M0 + wm * 32 + mt * 16 + (lane >> 4) * 4 + r;
        int n = n0 + wn * 64 + nt * 16 + (lane & 15);
        unsigned int pk = (unsigned int)f2bf(acc[mt][nt][0][r]) |
                          ((unsigned int)f2bf(acc[mt][nt][1][r]) << 16);
        BuP[(size_t)m * 256 + n] = pk;
      }

  {
    int q = lane >> 4;
    #pragma unroll
    for (int nt = 0; nt < 4; ++nt) {
      int n = n0 + wn * 64 + nt * 16 + (lane & 15);
      float lr = lamre[n], li = lamim[n];
      float hr[2], hi[2];
      #pragma unroll
      for (int mt = 0; mt < 2; ++mt) {
        float xr = 0.f, xi = 0.f;
        #pragma unroll
        for (int r = 0; r < 4; ++r) {
          float br = acc[mt][nt][0][r], bi = acc[mt][nt][1][r];
          float nr2 = lr * xr - li * xi + br;
          float ni2 = lr * xi + li * xr + bi;
          xr = nr2; xi = ni2;
        }
        hr[mt] = xr; hi[mt] = xi;
      }
      float l2r = lr * lr - li * li, l2i = 2.f * lr * li;
      float l4r = l2r * l2r - l2i * l2i, l4i = 2.f * l2r * l2i;
      float p8r = l4r * l4r - l4i * l4i, p8i = 2.f * l4r * l4i;
      float p12r = p8r * l4r - p8i * l4i, p12i = p8r * l4i + p8i * l4r;
      float p16r = p8r * p8r - p8i * p8i, p16i = 2.f * p8r * p8i;
      float e1r, e1i;
      if (q == 0)      { e1r = p12r; e1i = p12i; }
      else if (q == 1) { e1r = p8r;  e1i = p8i;  }
      else if (q == 2) { e1r = l4r;  e1i = l4i;  }
      else             { e1r = 1.f;  e1i = 0.f;  }
      float e0r = e1r * p16r - e1i * p16i;
      float e0i = e1r * p16i + e1i * p16r;
      float Tr = e0r * hr[0] - e0i * hi[0] + e1r * hr[1] - e1i * hi[1];
      float Ti = e0r * hi[0] + e0i * hr[0] + e1r * hi[1] + e1i * hr[1];
      Tr += __shfl_xor(Tr, 16); Ti += __shfl_xor(Ti, 16);
      Tr += __shfl_xor(Tr, 32); Ti += __shfl_xor(Ti, 32);
      if (q == 0) {
        size_t C = (size_t)mblk * 2 + wm;
        cl[C * 256 + n] = make_float2(Tr, Ti);
      }
    }
  }
}

// ---------------------------------------------------------------------------
// K2b: carry scan (green, unchanged).
// ---------------------------------------------------------------------------
__global__ void k2b_scan(const float2* __restrict__ cl, float2* __restrict__ cin,
                         const float* __restrict__ lamLre, const float* __restrict__ lamLim) {
  int b = blockIdx.x, n = threadIdx.x;
  float lr = lamLre[n], li = lamLim[n];
  float sr = 0.f, si = 0.f;
  #pragma unroll 4
  for (int c = 0; c < 128; ++c) {
    size_t idx = ((size_t)b * 128 + c) * 256 + n;
    float2 L = cl[idx];
    cin[idx] = make_float2(sr, si);
    float nr = lr * sr - li * si + L.x;
    float ni = lr * si + li * sr + L.y;
    sr = nr; si = ni;
  }
}

// ---------------------------------------------------------------------------
// K3a: f32 scan (green, unchanged). Reads packed Bu, overwrites with packed
// bf16 states (same thread/idx), writes inner-real f32 to second region.
// ---------------------------------------------------------------------------
__global__ __launch_bounds__(256) void k3a_scan(unsigned int* BuP, float* __restrict__ innerRe,
                                                const float2* __restrict__ cin,
                                                const float* __restrict__ lamre,
                                                const float* __restrict__ lamim) {
  int b = blockIdx.x >> 7, c = blockIdx.x & 127, n = threadIdx.x;
  size_t row0 = (size_t)b * 4096 + c * 32;
  float2 s0 = cin[((size_t)b * 128 + c) * 256 + n];
  float sr = s0.x, si = s0.y;
  float lr = lamre[n], li = lamim[n];
  #pragma unroll 4
  for (int j = 0; j < 32; ++j) {
    size_t idx = (row0 + j) * 256 + n;
    unsigned int v = BuP[idx];                          // read Bu FIRST
    BuP[idx] = (unsigned int)f2bf(sr) | ((unsigned int)f2bf(si) << 16);
    innerRe[idx] = sr;                                  // inner real (pre-state)
    float br = bf2f(v & 0xffffu), bi = bf2f(v >> 16);
    float nr = lr * sr - li * si + br;
    float ni = lr * si + li * sr + bi;
    sr = nr; si = ni;
  }
}

// ---------------------------------------------------------------------------
// K3b v3: B-register-stationary GEMM, M=64/block, 1024 threads (16 waves),
// wave w owns cols w*16..w*16+15. breg[2][4] dbuf (6 phases x 4 kk-steps);
// acc[4] covers 4 m-tiles. Halves W2t L2 traffic vs r13 (1024 blocks).
// Staging reads own SPack rows before barrier; epilogue overwrites after.
// ---------------------------------------------------------------------------
__global__ __launch_bounds__(1024, 4) void k3b_breg(const float* __restrict__ in,
                                                    const unsigned short* SPack,
                                                    const unsigned short* __restrict__ W2t,
                                                    float* outp) {
  __shared__ unsigned short lA[64 * 776];   // 99328 B
  int tid = threadIdx.x, lane = tid & 63, w = tid >> 6;   // w in [0,16)
  int l15 = lane & 15, q = lane >> 4;
  size_t row0 = (size_t)blockIdx.x * 64;

  s16x8 breg[2][4];                         // [buf][t]
  auto loadB = [&](int buf, int p) {
    #pragma unroll
    for (int t = 0; t < 4; ++t) {
      int kk = p * 4 + t;
      int c = w * 16 + l15;
      breg[buf][t] = *reinterpret_cast<const s16x8*>(
          W2t + ((size_t)kk * 256 + c) * 32 + q * 8);
    }
  };

  loadB(0, 0);                              // issue early, overlaps staging

  // stage lA cols 0..511: packed bf16 states (64 rows x 512 shorts)
  #pragma unroll
  for (int i = 0; i < 4; ++i) {
    int chunk = i * 1024 + tid;             // 4096 chunks of 8 shorts
    int r = chunk >> 6, c8 = (chunk & 63) * 8;
    *reinterpret_cast<uint4*>(&lA[r * 776 + c8]) =
        *reinterpret_cast<const uint4*>(SPack + (row0 + r) * 512 + c8);
  }
  // stage lA cols 512..767: u f32 -> bf16 (64 rows x 64 float4)
  #pragma unroll
  for (int i = 0; i < 4; ++i) {
    int chunk = i * 1024 + tid;             // 4096 float4 chunks
    int m = chunk >> 6, h0 = (chunk & 63) * 4;
    float4 v = *reinterpret_cast<const float4*>(in + (row0 + m) * 256 + h0);
    ushort4 s; s.x = f2bf(v.x); s.y = f2bf(v.y); s.z = f2bf(v.z); s.w = f2bf(v.w);
    *reinterpret_cast<ushort4*>(&lA[m * 776 + 512 + h0]) = s;
  }
  __syncthreads();

  f32x4 acc[4];
  #pragma unroll
  for (int mt = 0; mt < 4; ++mt) acc[mt] = f32x4{0.f, 0.f, 0.f, 0.f};

  #pragma unroll
  for (int p = 0; p < 6; ++p) {
    const int cur = p & 1;
    if (p < 5) loadB(cur ^ 1, p + 1);       // prefetch next phase into other buf
    #pragma unroll
    for (int t = 0; t < 4; ++t) {
      int kk = p * 4 + t;
      #pragma unroll
      for (int mt = 0; mt < 4; ++mt) {
        s16x8 af = *reinterpret_cast<const s16x8*>(
            &lA[(mt * 16 + l15) * 776 + kk * 32 + q * 8]);
        acc[mt] = mfma16(af, breg[cur][t], acc[mt]);
      }
    }
  }

  // epilogue: overwrite this block's own SPack rows with the final output
  #pragma unroll
  for (int mt = 0; mt < 4; ++mt)
    #pragma unroll
    for (int r = 0; r < 4; ++r) {
      size_t row = row0 + mt * 16 + q * 4 + r;
      int col = w * 16 + l15;
      outp[row * 256 + col] = acc[mt][r];
    }
}

// ---------------------------------------------------------------------------
extern "C" void kernel_launch(void* const* d_in, const int* in_sizes, int n_in,
                              void* d_out, int out_size, void* d_ws, size_t ws_size,
                              hipStream_t stream) {
  (void)in_sizes; (void)n_in; (void)out_size;
  const float* in       = (const float*)d_in[0];
  const float* nu_log   = (const float*)d_in[1];
  const float* theta_log= (const float*)d_in[2];
  const float* gamma_log= (const float*)d_in[3];
  const float* B_re     = (const float*)d_in[4];
  const float* B_im     = (const float*)d_in[5];
  const float* C_re     = (const float*)d_in[6];
  const float* C_im     = (const float*)d_in[7];
  const float* Dm       = (const float*)d_in[8];

  // ws: W1 [0,256K) | W2f [256K,1M) | lam @1M | W2t @1.25M | cl @2M (4M) | cin @6M (4M)
  if (ws_size < (size_t)10 * 1024 * 1024) return;
  char* ws = (char*)d_ws;
  unsigned short* W1 = (unsigned short*)(ws + 0);
  float* W2f   = (float*)(ws + 262144);
  float* lamre  = (float*)(ws + 1048576);
  float* lamim  = lamre + 256;
  float* lamLre = lamre + 512;
  float* lamLim = lamre + 768;
  unsigned short* W2t = (unsigned short*)(ws + 1310720);
  float2* cl  = (float2*)(ws + (size_t)2 * 1024 * 1024);
  float2* cin = (float2*)(ws + (size_t)6 * 1024 * 1024);

  unsigned int* BuP = (unsigned int*)d_out;                  // [0,64MB): Bu -> states -> output
  float* innerRe = (float*)d_out + (size_t)16777216;         // [64,128MB): inner real

  k0_mix<<<1281, 256, 0, stream>>>(nu_log, theta_log, gamma_log, B_re, B_im, C_re, C_im, Dm,
                                   W1, W2f, lamre, lamim, lamLre, lamLim);
  k0b_tile<<<768, 256, 0, stream>>>(W2f, W2t);
  k1_red<<<2048, 256, 0, stream>>>(in, W1, BuP, lamre, lamim, cl);
  k2b_scan<<<16, 256, 0, stream>>>(cl, cin, lamLre, lamLim);
  k3a_scan<<<2048, 256, 0, stream>>>(BuP, innerRe, cin, lamre, lamim);
  k3b_breg<<<1024, 1024, 0, stream>>>(in, (const unsigned short*)BuP, W2t, (float*)BuP);
}

// Round 17
// 146.097 us; speedup vs baseline: 8.6764x; 1.1366x over previous
//
#include <hip/hip_runtime.h>

// LRU r17: r16-green pipeline; ONLY k1 changed -> B-register-stationary
// (k3b-v3 pattern): M=64/block, 1024 thr, 16 waves x 16 cols (both planes),
// dbuf breg over 4 phases, 0 K-loop barriers, in-register chunk reduction.
// k3a/k3b split PERMANENT (r3/r4, r9/r10, r14/r15 all failed intra-kernel
// state->MFMA feeds; split is green).
// d_out = [0,64MB) output f32 | [64,128MB) inner-real f32.
// Region lifecycle:
//   [0,64MB):  k1 writes packed Bu (bf16 re|im u32) -> k3a reads then
//              overwrites per-thread with packed bf16 states -> k3b stages its
//              64 rows (before barrier) then epilogue overwrites with output.
//   [64,128MB): untouched until k3a writes inner-real f32 (exact, final).

typedef float  f32x4 __attribute__((ext_vector_type(4)));
typedef short  s16x8 __attribute__((ext_vector_type(8)));

__device__ __forceinline__ unsigned short f2bf(float x) {
  unsigned int u = __builtin_bit_cast(unsigned int, x);
  u += 0x7FFFu + ((u >> 16) & 1u);            // round-to-nearest-even
  return (unsigned short)(u >> 16);
}
__device__ __forceinline__ float bf2f(unsigned int s) {
  unsigned int u = s << 16;
  return __builtin_bit_cast(float, u);
}
__device__ __forceinline__ f32x4 mfma16(s16x8 a, s16x8 b, f32x4 c) {
  return __builtin_amdgcn_mfma_f32_16x16x32_bf16(a, b, c, 0, 0, 0);
}

// ---------------------------------------------------------------------------
// K0: W1 bf16 tiled + W2f f32 [k*256+o] + lam arrays (green, unchanged).
// ---------------------------------------------------------------------------
__global__ void k0_mix(const float* __restrict__ nu_log, const float* __restrict__ theta_log,
                       const float* __restrict__ gamma_log,
                       const float* __restrict__ B_re, const float* __restrict__ B_im,
                       const float* __restrict__ C_re, const float* __restrict__ C_im,
                       const float* __restrict__ Dm,
                       unsigned short* __restrict__ W1, float* __restrict__ W2f,
                       float* __restrict__ lamre, float* __restrict__ lamim,
                       float* __restrict__ lamLre, float* __restrict__ lamLim) {
  int idx = blockIdx.x * 256 + threadIdx.x;
  if (idx < 131072) {
    int ki = idx & 31; int np_ = (idx >> 5) & 511; int kk = idx >> 14;
    int k = kk * 32 + ki; int n = np_ & 255;
    float g = expf(gamma_log[n]);
    float v = (np_ < 256) ? B_re[n * 256 + k] : B_im[n * 256 + k];
    W1[idx] = f2bf(g * v);
  } else if (idx < 327680) {
    int j = idx - 131072;
    int k = j >> 8, o = j & 255;
    float v;
    if (k < 512) { int n = k >> 1; v = (k & 1) ? -C_im[o * 256 + n] : C_re[o * 256 + n]; }
    else         { v = Dm[o * 256 + (k - 512)]; }
    W2f[j] = v;
  } else if (idx < 327936) {
    int n = idx - 327680;
    float la = expf(-expf(nu_log[n]));
    float th = expf(theta_log[n]);
    float lr = la * cosf(th), li = la * sinf(th);
    lamre[n] = lr; lamim[n] = li;
    float r = lr, i = li;
    #pragma unroll
    for (int t = 0; t < 5; ++t) { float nr = r * r - i * i; float ni = 2.f * r * i; r = nr; i = ni; }
    lamLre[n] = r; lamLim[n] = i;
  }
}

// ---------------------------------------------------------------------------
// K0b: tile W2f into bf16 W2t[(kk*256+o)*32+ki] (green, unchanged).
// ---------------------------------------------------------------------------
__global__ void k0b_tile(const float* __restrict__ W2f, unsigned short* __restrict__ W2t) {
  int j = blockIdx.x * 256 + threadIdx.x;          // [0,196608)
  int ki = j & 31, o = (j >> 5) & 255, kk = j >> 13;
  W2t[j] = f2bf(W2f[(kk * 32 + ki) * 256 + o]);
}

// ---------------------------------------------------------------------------
// K1 v2: B-register-stationary Bu-GEMM + packed stores + in-register chunk
// reduction. M=64/block, 1024 threads (16 waves); wave w owns cols
// n = w*16..w*16+15 of BOTH re/im planes. breg[2][2][2] dbuf (4 phases x
// 2 kk-steps). One barrier total. acc[mt][p]: rows mt*16+q*4+r.
// ---------------------------------------------------------------------------
__global__ __launch_bounds__(1024, 4) void k1_bstat(const float* __restrict__ in,
                                                    const unsigned short* __restrict__ W1,
                                                    unsigned int* __restrict__ BuP,
                                                    const float* __restrict__ lamre,
                                                    const float* __restrict__ lamim,
                                                    float2* __restrict__ cl) {
  __shared__ unsigned short lA[64 * 264];   // 33792 B
  int tid = threadIdx.x, lane = tid & 63, w = tid >> 6;   // w in [0,16)
  int l15 = lane & 15, q = lane >> 4;
  int n = w * 16 + l15;
  size_t row0 = (size_t)blockIdx.x * 64;

  s16x8 breg[2][2][2];                      // [buf][plane][t]
  auto loadB = [&](int buf, int ph) {
    #pragma unroll
    for (int p = 0; p < 2; ++p)
      #pragma unroll
      for (int t = 0; t < 2; ++t) {
        int kk = ph * 2 + t;
        breg[buf][p][t] = *reinterpret_cast<const s16x8*>(
            W1 + (size_t)(kk * 512 + p * 256 + n) * 32 + q * 8);
      }
  };

  loadB(0, 0);                              // issue early, overlaps staging

  // stage lA: 64 rows x 256 f32 -> bf16 (k3b-v3 staging pattern)
  #pragma unroll
  for (int i = 0; i < 4; ++i) {
    int chunk = i * 1024 + tid;             // 4096 float4 chunks
    int m = chunk >> 6, h0 = (chunk & 63) * 4;
    float4 v = *reinterpret_cast<const float4*>(in + (row0 + m) * 256 + h0);
    ushort4 s; s.x = f2bf(v.x); s.y = f2bf(v.y); s.z = f2bf(v.z); s.w = f2bf(v.w);
    *reinterpret_cast<ushort4*>(&lA[m * 264 + h0]) = s;
  }
  __syncthreads();

  f32x4 acc[4][2];
  #pragma unroll
  for (int mt = 0; mt < 4; ++mt)
    #pragma unroll
    for (int p = 0; p < 2; ++p) acc[mt][p] = f32x4{0.f, 0.f, 0.f, 0.f};

  #pragma unroll
  for (int ph = 0; ph < 4; ++ph) {
    const int cur = ph & 1;
    if (ph < 3) loadB(cur ^ 1, ph + 1);     // prefetch next phase into other buf
    #pragma unroll
    for (int t = 0; t < 2; ++t) {
      int kk = ph * 2 + t;
      #pragma unroll
      for (int mt = 0; mt < 4; ++mt) {
        s16x8 af = *reinterpret_cast<const s16x8*>(
            &lA[(mt * 16 + l15) * 264 + kk * 32 + q * 8]);
        acc[mt][0] = mfma16(af, breg[cur][0][t], acc[mt][0]);
        acc[mt][1] = mfma16(af, breg[cur][1][t], acc[mt][1]);
      }
    }
  }

  // epilogue: pack (re,im) bf16 pairs
  #pragma unroll
  for (int mt = 0; mt < 4; ++mt)
    #pragma unroll
    for (int r = 0; r < 4; ++r) {
      size_t row = row0 + mt * 16 + q * 4 + r;
      unsigned int pk = (unsigned int)f2bf(acc[mt][0][r]) |
                        ((unsigned int)f2bf(acc[mt][1][r]) << 16);
      BuP[row * 256 + n] = pk;
    }

  // in-register chunk reduction: 2 chunks (rows 0..31 via mt 0,1; 32..63 via
  // mt 2,3). t = mt'*16+q*4+r; 31-t = (3-r)+(28-16mt'-4q) ->
  // X = lam^{28-4q} H0 + lam^{12-4q} H1 (r11-green algebra, nt-loop removed).
  {
    float lr = lamre[n], li = lamim[n];
    float l2r = lr * lr - li * li, l2i = 2.f * lr * li;
    float l4r = l2r * l2r - l2i * l2i, l4i = 2.f * l2r * l2i;
    float p8r = l4r * l4r - l4i * l4i, p8i = 2.f * l4r * l4i;
    float p12r = p8r * l4r - p8i * l4i, p12i = p8r * l4i + p8i * l4r;
    float p16r = p8r * p8r - p8i * p8i, p16i = 2.f * p8r * p8i;
    float e1r, e1i;                         // lam^{12-4q}
    if (q == 0)      { e1r = p12r; e1i = p12i; }
    else if (q == 1) { e1r = p8r;  e1i = p8i;  }
    else if (q == 2) { e1r = l4r;  e1i = l4i;  }
    else             { e1r = 1.f;  e1i = 0.f;  }
    float e0r = e1r * p16r - e1i * p16i;    // lam^{28-4q}
    float e0i = e1r * p16i + e1i * p16r;
    #pragma unroll
    for (int ch = 0; ch < 2; ++ch) {
      float hr[2], hi[2];
      #pragma unroll
      for (int h = 0; h < 2; ++h) {
        int mt = ch * 2 + h;
        float xr = 0.f, xi = 0.f;
        #pragma unroll
        for (int r = 0; r < 4; ++r) {
          float br = acc[mt][0][r], bi2 = acc[mt][1][r];
          float nr2 = lr * xr - li * xi + br;
          float ni2 = lr * xi + li * xr + bi2;
          xr = nr2; xi = ni2;
        }
        hr[h] = xr; hi[h] = xi;
      }
      float Tr = e0r * hr[0] - e0i * hi[0] + e1r * hr[1] - e1i * hi[1];
      float Ti = e0r * hi[0] + e0i * hr[0] + e1r * hi[1] + e1i * hr[1];
      Tr += __shfl_xor(Tr, 16); Ti += __shfl_xor(Ti, 16);
      Tr += __shfl_xor(Tr, 32); Ti += __shfl_xor(Ti, 32);
      if (q == 0) {
        size_t C = (size_t)blockIdx.x * 2 + ch;
        cl[C * 256 + n] = make_float2(Tr, Ti);
      }
    }
  }
}

// ---------------------------------------------------------------------------
// K2b: carry scan (green, unchanged).
// ---------------------------------------------------------------------------
__global__ void k2b_scan(const float2* __restrict__ cl, float2* __restrict__ cin,
                         const float* __restrict__ lamLre, const float* __restrict__ lamLim) {
  int b = blockIdx.x, n = threadIdx.x;
  float lr = lamLre[n], li = lamLim[n];
  float sr = 0.f, si = 0.f;
  #pragma unroll 4
  for (int c = 0; c < 128; ++c) {
    size_t idx = ((size_t)b * 128 + c) * 256 + n;
    float2 L = cl[idx];
    cin[idx] = make_float2(sr, si);
    float nr = lr * sr - li * si + L.x;
    float ni = lr * si + li * sr + L.y;
    sr = nr; si = ni;
  }
}

// ---------------------------------------------------------------------------
// K3a: f32 scan (green, unchanged). Reads packed Bu, overwrites with packed
// bf16 states (same thread/idx), writes inner-real f32 to second region.
// ---------------------------------------------------------------------------
__global__ __launch_bounds__(256) void k3a_scan(unsigned int* BuP, float* __restrict__ innerRe,
                                                const float2* __restrict__ cin,
                                                const float* __restrict__ lamre,
                                                const float* __restrict__ lamim) {
  int b = blockIdx.x >> 7, c = blockIdx.x & 127, n = threadIdx.x;
  size_t row0 = (size_t)b * 4096 + c * 32;
  float2 s0 = cin[((size_t)b * 128 + c) * 256 + n];
  float sr = s0.x, si = s0.y;
  float lr = lamre[n], li = lamim[n];
  #pragma unroll 4
  for (int j = 0; j < 32; ++j) {
    size_t idx = (row0 + j) * 256 + n;
    unsigned int v = BuP[idx];                          // read Bu FIRST
    BuP[idx] = (unsigned int)f2bf(sr) | ((unsigned int)f2bf(si) << 16);
    innerRe[idx] = sr;                                  // inner real (pre-state)
    float br = bf2f(v & 0xffffu), bi = bf2f(v >> 16);
    float nr = lr * sr - li * si + br;
    float ni = lr * si + li * sr + bi;
    sr = nr; si = ni;
  }
}

// ---------------------------------------------------------------------------
// K3b v3 (green r16, unchanged): B-register-stationary output GEMM,
// M=64/block, 1024 threads (16 waves), wave w owns cols w*16..w*16+15.
// ---------------------------------------------------------------------------
__global__ __launch_bounds__(1024, 4) void k3b_breg(const float* __restrict__ in,
                                                    const unsigned short* SPack,
                                                    const unsigned short* __restrict__ W2t,
                                                    float* outp) {
  __shared__ unsigned short lA[64 * 776];   // 99328 B
  int tid = threadIdx.x, lane = tid & 63, w = tid >> 6;   // w in [0,16)
  int l15 = lane & 15, q = lane >> 4;
  size_t row0 = (size_t)blockIdx.x * 64;

  s16x8 breg[2][4];                         // [buf][t]
  auto loadB = [&](int buf, int p) {
    #pragma unroll
    for (int t = 0; t < 4; ++t) {
      int kk = p * 4 + t;
      int c = w * 16 + l15;
      breg[buf][t] = *reinterpret_cast<const s16x8*>(
          W2t + ((size_t)kk * 256 + c) * 32 + q * 8);
    }
  };

  loadB(0, 0);                              // issue early, overlaps staging

  // stage lA cols 0..511: packed bf16 states (64 rows x 512 shorts)
  #pragma unroll
  for (int i = 0; i < 4; ++i) {
    int chunk = i * 1024 + tid;             // 4096 chunks of 8 shorts
    int r = chunk >> 6, c8 = (chunk & 63) * 8;
    *reinterpret_cast<uint4*>(&lA[r * 776 + c8]) =
        *reinterpret_cast<const uint4*>(SPack + (row0 + r) * 512 + c8);
  }
  // stage lA cols 512..767: u f32 -> bf16 (64 rows x 64 float4)
  #pragma unroll
  for (int i = 0; i < 4; ++i) {
    int chunk = i * 1024 + tid;             // 4096 float4 chunks
    int m = chunk >> 6, h0 = (chunk & 63) * 4;
    float4 v = *reinterpret_cast<const float4*>(in + (row0 + m) * 256 + h0);
    ushort4 s; s.x = f2bf(v.x); s.y = f2bf(v.y); s.z = f2bf(v.z); s.w = f2bf(v.w);
    *reinterpret_cast<ushort4*>(&lA[m * 776 + 512 + h0]) = s;
  }
  __syncthreads();

  f32x4 acc[4];
  #pragma unroll
  for (int mt = 0; mt < 4; ++mt) acc[mt] = f32x4{0.f, 0.f, 0.f, 0.f};

  #pragma unroll
  for (int p = 0; p < 6; ++p) {
    const int cur = p & 1;
    if (p < 5) loadB(cur ^ 1, p + 1);       // prefetch next phase into other buf
    #pragma unroll
    for (int t = 0; t < 4; ++t) {
      int kk = p * 4 + t;
      #pragma unroll
      for (int mt = 0; mt < 4; ++mt) {
        s16x8 af = *reinterpret_cast<const s16x8*>(
            &lA[(mt * 16 + l15) * 776 + kk * 32 + q * 8]);
        acc[mt] = mfma16(af, breg[cur][t], acc[mt]);
      }
    }
  }

  // epilogue: overwrite this block's own SPack rows with the final output
  #pragma unroll
  for (int mt = 0; mt < 4; ++mt)
    #pragma unroll
    for (int r = 0; r < 4; ++r) {
      size_t row = row0 + mt * 16 + q * 4 + r;
      int col = w * 16 + l15;
      outp[row * 256 + col] = acc[mt][r];
    }
}

// ---------------------------------------------------------------------------
extern "C" void kernel_launch(void* const* d_in, const int* in_sizes, int n_in,
                              void* d_out, int out_size, void* d_ws, size_t ws_size,
                              hipStream_t stream) {
  (void)in_sizes; (void)n_in; (void)out_size;
  const float* in       = (const float*)d_in[0];
  const float* nu_log   = (const float*)d_in[1];
  const float* theta_log= (const float*)d_in[2];
  const float* gamma_log= (const float*)d_in[3];
  const float* B_re     = (const float*)d_in[4];
  const float* B_im     = (const float*)d_in[5];
  const float* C_re     = (const float*)d_in[6];
  const float* C_im     = (const float*)d_in[7];
  const float* Dm       = (const float*)d_in[8];

  // ws: W1 [0,256K) | W2f [256K,1M) | lam @1M | W2t @1.25M | cl @2M (4M) | cin @6M (4M)
  if (ws_size < (size_t)10 * 1024 * 1024) return;
  char* ws = (char*)d_ws;
  unsigned short* W1 = (unsigned short*)(ws + 0);
  float* W2f   = (float*)(ws + 262144);
  float* lamre  = (float*)(ws + 1048576);
  float* lamim  = lamre + 256;
  float* lamLre = lamre + 512;
  float* lamLim = lamre + 768;
  unsigned short* W2t = (unsigned short*)(ws + 1310720);
  float2* cl  = (float2*)(ws + (size_t)2 * 1024 * 1024);
  float2* cin = (float2*)(ws + (size_t)6 * 1024 * 1024);

  unsigned int* BuP = (unsigned int*)d_out;                  // [0,64MB): Bu -> states -> output
  float* innerRe = (float*)d_out + (size_t)16777216;         // [64,128MB): inner real

  k0_mix<<<1281, 256, 0, stream>>>(nu_log, theta_log, gamma_log, B_re, B_im, C_re, C_im, Dm,
                                   W1, W2f, lamre, lamim, lamLre, lamLim);
  k0b_tile<<<768, 256, 0, stream>>>(W2f, W2t);
  k1_bstat<<<1024, 1024, 0, stream>>>(in, W1, BuP, lamre, lamim, cl);
  k2b_scan<<<16, 256, 0, stream>>>(cl, cin, lamLre, lamLim);
  k3a_scan<<<2048, 256, 0, stream>>>(BuP, innerRe, cin, lamre, lamim);
  k3b_breg<<<1024, 1024, 0, stream>>>(in, (const unsigned short*)BuP, W2t, (float*)BuP);
}